// Round 13
// baseline (326.576 us; speedup 1.0000x reference)
//
#include <hip/hip_runtime.h>
#include <hip/hip_bf16.h>
#include <math.h>

typedef __hip_bfloat16 bf16;

#define HB 8
#define HH 56
#define WWD 56
#define DD 256
#define NHEAD 8
#define KDIM 32
#define FFND 1024
#define NPIX (HB*HH*WWD)             /* 25088 */
#define SCALE_K 0.17677669529663687f /* 32^-0.5 */

typedef __attribute__((ext_vector_type(8))) short short8;   // 8 bf16 (4 VGPRs)
typedef __attribute__((ext_vector_type(4))) float f32x4;

__device__ inline float toF(float x){ return x; }
__device__ inline float toF(bf16 x){ return __bfloat162float(x); }

__device__ inline float bfu_to_f(unsigned short u){
    union { float f; unsigned u32; } cv; cv.u32 = (unsigned)u << 16; return cv.f;
}

__device__ inline unsigned short f2bu(float f){
    union { bf16 b; unsigned short u; } cv; cv.b = __float2bfloat16(f); return cv.u;
}
__device__ inline unsigned pk2(float a, float b){
    return (unsigned)f2bu(a) | ((unsigned)f2bu(b) << 16);
}

// fast GELU: 0.5*y*(1+tanh(0.79788456*(y+0.044715*y^3))) = y*sigmoid(2u)
__device__ inline float gelu_fast(float y){
    const float u2 = y*y;
    const float arg = y * (2.302208219f + 0.1029402445f*u2);
    const float e2 = exp2f(fminf(arg, 126.0f));
    return y * e2 / (e2 + 1.0f);
}

// async global->LDS, 16B per lane; dest = wave-uniform base + lane*16 (HW adds it)
__device__ inline void gl16(const bf16* g, unsigned short* l){
    __builtin_amdgcn_global_load_lds((const __attribute__((address_space(1))) void*)g,
                                     (__attribute__((address_space(3))) void*)l, 16, 0, 0);
}

// ---- one-shot init: bf16 weights + rope table + concat qkv bias ----
__global__ __launch_bounds__(256) void init_kernel(
    const float* __restrict__ wq, const float* __restrict__ wk,
    const float* __restrict__ wv, const float* __restrict__ wo,
    const float* __restrict__ f1, const float* __restrict__ f2,
    const float* __restrict__ bq, const float* __restrict__ bk,
    const float* __restrict__ bv,
    bf16* __restrict__ dst, float2* __restrict__ ropet, float* __restrict__ bqkv)
{
    const int id = blockIdx.x*256 + threadIdx.x;   // 149248 total
    if (id < 98304) {
        const float* src; int off;
        if      (id < 8192)  { src = wq; off = id; }
        else if (id < 16384) { src = wk; off = id - 8192; }
        else if (id < 24576) { src = wv; off = id - 16384; }
        else if (id < 32768) { src = wo; off = id - 24576; }
        else if (id < 65536) { src = f1; off = id - 32768; }
        else                 { src = f2; off = id - 65536; }
        const float4 a = *(const float4*)(src + (size_t)off*8);
        const float4 b = *(const float4*)(src + (size_t)off*8 + 4);
        uint4 v; v.x = pk2(a.x,a.y); v.y = pk2(a.z,a.w); v.z = pk2(b.x,b.y); v.w = pk2(b.z,b.w);
        *(uint4*)(dst + (size_t)id*8) = v;
    } else if (id < 148480) {
        const int rid = id - 98304;                // 50176 rope entries
        const int idx = rid >> 4, i = rid & 15;
        const float ph = (float)idx * exp2f(-(float)i * 0.88584749196996324f);
        ropet[rid] = make_float2(cosf(ph), sinf(ph));
    } else {
        const int b = id - 148480;                 // 768 bias
        bqkv[b] = (b < 256) ? bq[b] : ((b < 512) ? bk[b-256] : bv[b-512]);
    }
}

// ---- CPE + LN1 fused, sliding-window ----
__global__ __launch_bounds__(256) void cpe_ln_slide_kernel(
    const float* __restrict__ x, const float* __restrict__ wt,
    const float* __restrict__ bias, const float* __restrict__ g,
    const float* __restrict__ bln, float* __restrict__ X0, bf16* __restrict__ B1)
{
    constexpr int C = 256, VEC = 4, NPX = 4, KS = 3, P = 1, NX = NPX + KS - 1;
    constexpr int GPR = WWD / NPX;          // 14 groups per row
    constexpr int NB  = NPIX / (NPX * 4);   // 1568 blocks
    const int tid  = threadIdx.x;
    const int wv   = tid >> 6;
    const int lane = tid & 63;
    const int bid  = blockIdx.x;
    const int swb  = (bid & 7) * (NB >> 3) + (bid >> 3);   // XCD-chunked
    const int gid  = swb * 4 + wv;
    const int row  = gid / GPR;             // 0..447 (b*56 + h)
    const int w0   = (gid % GPR) * NPX;
    const int h    = row % HH;
    const int b    = row / HH;
    const int c0   = lane * VEC;

    float acc[NPX][VEC];
    {
        const float4 b0 = *(const float4*)(bias + c0);
        #pragma unroll
        for (int j = 0; j < NPX; j++) {
            acc[j][0] = b0.x; acc[j][1] = b0.y; acc[j][2] = b0.z; acc[j][3] = b0.w;
        }
    }

    #pragma unroll
    for (int ky = 0; ky < KS; ky++) {
        const int hh = h + ky - P;
        if (hh < 0 || hh >= HH) continue;
        const float* rowp = x + ((size_t)(b*HH + hh) * WWD) * C + c0;
        float wvv[KS][VEC];
        #pragma unroll
        for (int kx = 0; kx < KS; kx++) {
            const float4 w4 = *(const float4*)(wt + (size_t)(ky*KS + kx)*C + c0);
            wvv[kx][0] = w4.x; wvv[kx][1] = w4.y; wvv[kx][2] = w4.z; wvv[kx][3] = w4.w;
        }
        #pragma unroll
        for (int xc = 0; xc < NX; xc++) {
            const int ww = w0 - P + xc;
            float4 f0 = {0.f, 0.f, 0.f, 0.f};
            if (ww >= 0 && ww < WWD) f0 = *(const float4*)(rowp + (size_t)ww*C);
            const float fv[VEC] = {f0.x, f0.y, f0.z, f0.w};
            #pragma unroll
            for (int j = 0; j < NPX; j++) {
                const int kx = xc - j;
                if (kx < 0 || kx >= KS) continue;
                #pragma unroll
                for (int e = 0; e < VEC; e++)
                    acc[j][e] += fv[e] * wvv[kx][e];
            }
        }
    }

    const float4 gv = *(const float4*)(g + c0);
    const float4 bv = *(const float4*)(bln + c0);
    #pragma unroll
    for (int j = 0; j < NPX; j++) {
        const size_t obase = ((size_t)row*WWD + w0 + j)*C + c0;
        {   // + input (residual trunk)
            const float4 r0 = *(const float4*)(x + obase);
            acc[j][0] += r0.x; acc[j][1] += r0.y; acc[j][2] += r0.z; acc[j][3] += r0.w;
        }
        { float4 o; o.x = acc[j][0]; o.y = acc[j][1]; o.z = acc[j][2]; o.w = acc[j][3];
          *(float4*)(X0 + obase) = o; }
        float s1 = acc[j][0] + acc[j][1] + acc[j][2] + acc[j][3];
        float s2 = acc[j][0]*acc[j][0] + acc[j][1]*acc[j][1]
                 + acc[j][2]*acc[j][2] + acc[j][3]*acc[j][3];
        #pragma unroll
        for (int d = 1; d < 64; d <<= 1) { s1 += __shfl_xor(s1, d); s2 += __shfl_xor(s2, d); }
        const float mu  = s1 * (1.0f/DD);
        const float var = s2 * (1.0f/DD) - mu*mu;
        const float inv = rsqrtf(var + 1e-6f);
        uint2 o2;
        o2.x = pk2((acc[j][0]-mu)*inv*gv.x + bv.x, (acc[j][1]-mu)*inv*gv.y + bv.y);
        o2.y = pk2((acc[j][2]-mu)*inv*gv.z + bv.z, (acc[j][3]-mu)*inv*gv.w + bv.w);
        *(uint2*)(B1 + obase) = o2;
    }
}

// ---- sliding-window depthwise conv, bf16, VEC=8 ch/thread, 4 px/thread. ----
template<int KS, bool ADD, int C>
__global__ __launch_bounds__(256) void dwconv_slide_kernel(
    const bf16* __restrict__ in, const float* __restrict__ wt, int wst,
    const float* __restrict__ bias, bf16* __restrict__ out)
{
    constexpr int VEC = 8, CG = C/VEC, GPB = 256/CG, NPX = 4, P = KS/2, NX = NPX+KS-1;
    constexpr int GPR = WWD/NPX;          // 14 groups per row
    constexpr int NB  = NPIX/(NPX*GPB);   // grid size
    const int tid = threadIdx.x;
    const int cg  = tid % CG;
    const int gl  = tid / CG;
    const int bid = blockIdx.x;
    const int swb = (bid & 7) * (NB >> 3) + (bid >> 3);   // XCD-chunked
    const int gid = swb * GPB + gl;
    const int row = gid / GPR;            // 0..447 (b*56 + h)
    const int w0  = (gid % GPR) * NPX;
    const int h   = row % HH;
    const int b   = row / HH;
    const int c0  = cg * VEC;

    float acc[NPX][VEC];
    {
        const float4 b0 = *(const float4*)(bias + c0);
        const float4 b1 = *(const float4*)(bias + c0 + 4);
        #pragma unroll
        for (int j = 0; j < NPX; j++) {
            acc[j][0]=b0.x; acc[j][1]=b0.y; acc[j][2]=b0.z; acc[j][3]=b0.w;
            acc[j][4]=b1.x; acc[j][5]=b1.y; acc[j][6]=b1.z; acc[j][7]=b1.w;
        }
    }

    #pragma unroll
    for (int ky = 0; ky < KS; ky++) {
        const int hh = h + ky - P;
        if (hh < 0 || hh >= HH) continue;
        const bf16* rowp = in + ((size_t)(b*HH + hh) * WWD) * C + c0;
        float wv[KS][VEC];
        #pragma unroll
        for (int kx = 0; kx < KS; kx++) {
            const float* wp = wt + (size_t)(ky*KS + kx)*wst + c0;
            const float4 w0v = *(const float4*)(wp);
            const float4 w1v = *(const float4*)(wp + 4);
            wv[kx][0]=w0v.x; wv[kx][1]=w0v.y; wv[kx][2]=w0v.z; wv[kx][3]=w0v.w;
            wv[kx][4]=w1v.x; wv[kx][5]=w1v.y; wv[kx][6]=w1v.z; wv[kx][7]=w1v.w;
        }
        #pragma unroll
        for (int x = 0; x < NX; x++) {
            const int ww = w0 - P + x;
            short8 raw = {0,0,0,0,0,0,0,0};
            if (ww >= 0 && ww < WWD) raw = *(const short8*)(rowp + (size_t)ww*C);
            float f[VEC];
            #pragma unroll
            for (int e = 0; e < VEC; e++) f[e] = bfu_to_f((unsigned short)raw[e]);
            #pragma unroll
            for (int j = 0; j < NPX; j++) {
                const int kx = x - j;
                if (kx < 0 || kx >= KS) continue;
                #pragma unroll
                for (int e = 0; e < VEC; e++)
                    acc[j][e] += f[e] * wv[kx][e];
            }
        }
    }

    #pragma unroll
    for (int j = 0; j < NPX; j++) {
        const size_t obase = ((size_t)row*WWD + w0 + j)*C + c0;
        if constexpr (ADD) {
            short8 vv = *(const short8*)(in + obase);
            #pragma unroll
            for (int e = 0; e < VEC; e++) acc[j][e] += bfu_to_f((unsigned short)vv[e]);
        }
        uint4 o;
        o.x = pk2(acc[j][0], acc[j][1]); o.y = pk2(acc[j][2], acc[j][3]);
        o.z = pk2(acc[j][4], acc[j][5]); o.w = pk2(acc[j][6], acc[j][7]);
        *(uint4*)(out + obase) = o;
    }
}

// ---- MFMA GEMM: 128x128 tile, 4 waves (2x2), acc[4][4], BK=32, bf16 weights.
// Depth-2 pipeline (3 LDS buffers, gl16, counted vmcnt) + T2 swizzle.
// Used only for the fused QKV projection (EPI=3).
template<int EPI, int ROPE>
__global__ __launch_bounds__(256) void mgemm128_kernel(
    const bf16* __restrict__ A, const bf16* __restrict__ Wb, int ldw,
    const float* __restrict__ bias, const float2* __restrict__ ropet,
    bf16* __restrict__ outB, bf16* __restrict__ outK, bf16* __restrict__ outV,
    int M, int N, int K, float scale)
{
    __shared__ __align__(16) unsigned short Sh[24576];  // 48KB: 3 x (As 8KB | Bs 8KB)
    const int tid  = threadIdx.x;
    const int wid  = tid >> 6;
    const int lane = tid & 63;
    const int quad = lane >> 4;
    const int l15  = lane & 15;
    const int wr   = wid >> 1;
    const int wc   = wid & 1;
    const int sw   = (l15 >> 1) & 3;     // frag-read chunk swizzle (= (row>>1)&3)

    // XCD-chunked tile swizzle (T divisible by 8)
    const int NXg = gridDim.x;
    const int T   = NXg * gridDim.y;
    int f = blockIdx.y * NXg + blockIdx.x;
    f = (f & 7) * (T >> 3) + (f >> 3);
    const int row0 = (f / NXg) * 128;
    const int col0 = (f % NXg) * 128;

    f32x4 acc[4][4];
    #pragma unroll
    for (int m = 0; m < 4; m++)
        #pragma unroll
        for (int n = 0; n < 4; n++)
            acc[m][n] = (f32x4){0.f, 0.f, 0.f, 0.f};

    const int ob0 = (wid*2 + 0)*64;          // wave-uniform 16B-unit bases
    const int ob1 = (wid*2 + 1)*64;
    const int o0  = ob0 + lane, o1 = ob1 + lane;
    const int rA0 = o0 >> 2, ch0 = ((o0 & 3) ^ ((o0 >> 3) & 3)) * 8;
    const int rA1 = o1 >> 2, ch1 = ((o1 & 3) ^ ((o1 >> 3) & 3)) * 8;
    const bf16* pA0 = A  + (size_t)(row0 + rA0)*K   + ch0;
    const bf16* pA1 = A  + (size_t)(row0 + rA1)*K   + ch1;
    const bf16* pW0 = Wb + (size_t)(col0 + rA0)*ldw + ch0;
    const bf16* pW1 = Wb + (size_t)(col0 + rA1)*ldw + ch1;

    #define STAGE(bi) { unsigned short* As_ = Sh + (bi)*8192;                  \
                        unsigned short* Bs_ = As_ + 4096;                      \
                        gl16(pA0, &As_[ob0*8]); gl16(pA1, &As_[ob1*8]);        \
                        gl16(pW0, &Bs_[ob0*8]); gl16(pW1, &Bs_[ob1*8]);        \
                        pA0 += 32; pA1 += 32; pW0 += 32; pW1 += 32; }

    #define COMPUTE(bi) { const unsigned short* As_ = Sh + (bi)*8192;          \
                          const unsigned short* Bs_ = As_ + 4096;              \
                          short8 af[4], bfr[4];                                \
                          _Pragma("unroll")                                    \
                          for (int m = 0; m < 4; m++)                          \
                              af[m] = *(const short8*)(&As_[(wr*64 + m*16 + l15)*32 + (quad ^ sw)*8]); \
                          _Pragma("unroll")                                    \
                          for (int n = 0; n < 4; n++)                          \
                              bfr[n] = *(const short8*)(&Bs_[(wc*64 + n*16 + l15)*32 + (quad ^ sw)*8]); \
                          _Pragma("unroll")                                    \
                          for (int m = 0; m < 4; m++)                          \
                              _Pragma("unroll")                                \
                              for (int n = 0; n < 4; n++)                      \
                                  acc[m][n] = __builtin_amdgcn_mfma_f32_16x16x32_bf16(af[m], bfr[n], acc[m][n], 0, 0, 0); }

    const int nt = K >> 5;                      // 8, always >= 3
    STAGE(0); STAGE(1);                         // tiles 0,1 in flight
    int cur = 0;
    for (int t = 0; t < nt; t++) {
        if (t + 2 < nt) {
            const int nx = (cur == 0) ? 2 : ((cur == 1) ? 0 : 1);   // (cur+2)%3
            STAGE(nx);
            asm volatile("s_waitcnt vmcnt(8)" ::: "memory");
        } else if (t + 1 < nt) {
            asm volatile("s_waitcnt vmcnt(4)" ::: "memory");
        } else {
            asm volatile("s_waitcnt vmcnt(0)" ::: "memory");
        }
        __builtin_amdgcn_s_barrier();
        COMPUTE(cur);
        if (t + 1 < nt) __builtin_amdgcn_s_barrier();
        cur = (cur == 2) ? 0 : cur + 1;
    }
    #undef STAGE
    #undef COMPUTE

    // ---- epilogue: per-wave LDS transpose -> coalesced stores ----
    __syncthreads();
    float* Ls = (float*)Sh;
    const int cbl = l15 * 4;
    const int seg = (col0 >> 8);
    bf16* dst = (seg == 0) ? outB : ((seg == 1) ? outK : outV);
    const float esc = (seg == 1) ? scale : 1.0f;
    const bool doRope = ROPE && (seg < 2);

    #pragma unroll
    for (int m = 0; m < 4; m++) {
        #pragma unroll
        for (int n = 0; n < 4; n++) {
            const int col = n*16 + l15;
            const float bval = bias[col0 + wc*64 + col];
            #pragma unroll
            for (int reg = 0; reg < 4; reg++)
                Ls[wid*1088 + (quad*4+reg)*68 + col] = (acc[m][n][reg] + bval) * esc;
        }
        #pragma unroll
        for (int p = 0; p < 4; p++) {
            const int rowt = p*4 + quad;
            const float4 v = *(const float4*)&Ls[wid*1088 + rowt*68 + cbl];
            const int mm = row0 + wr*64 + m*16 + rowt;
            const int ncl = (col0 & 255) + wc*64 + cbl;
            const size_t o = (size_t)mm * 256 + ncl;
            float a = v.x, b = v.y, c = v.z, d = v.w;
            if (doRope) {
                const int idx = mm % (HH*WWD);
                const int i0 = (ncl & 31) >> 1;
                const float4 t = *(const float4*)&ropet[(size_t)idx*16 + i0];
                const float na  = a*t.x - b*t.y;
                const float nb  = b*t.x + a*t.y;
                const float ncv = c*t.z - d*t.w;
                const float nd  = d*t.z + c*t.w;
                a = na; b = nb; c = ncv; d = nd;
            }
            uint2 ov; ov.x = pk2(a, b); ov.y = pk2(c, d);
            *(uint2*)(dst + o) = ov;
        }
    }
}

// ---- 512-thread 128x256-tile GEMM, 8 waves (2 row x 4 col), depth-1 gl16
// double-buffer, T2 swizzle. EPI: 0 = fast-GELU bf16 out (col0 offset, fc1)
//                               1 = WO+residual+LN2 (accF = x1, outB = LN bf16)
//                               2 = fc2+residual (accF = final fp32)
template<int EPI>
__global__ __launch_bounds__(512) void mgemm_wide_kernel(
    const bf16* __restrict__ A, const bf16* __restrict__ Wb,
    const float* __restrict__ bias, const float* __restrict__ residF,
    float* __restrict__ accF, const float* __restrict__ g,
    const float* __restrict__ bln, bf16* __restrict__ outB, int K, int N)
{
    __shared__ __align__(16) unsigned short Sh[24576];  // 48KB: 2 x (As 8KB | Bs 16KB)
    const int tid  = threadIdx.x;
    const int wid  = tid >> 6;          // 0..7
    const int lane = tid & 63;
    const int quad = lane >> 4;
    const int l15  = lane & 15;
    const int wr   = wid >> 2;          // 0..1  (64-row half)
    const int wc   = wid & 3;           // 0..3  (64-col quarter)
    const int sw   = (l15 >> 1) & 3;

    // flatten + optional XCD-chunked swizzle (only if total blocks % 8 == 0)
    const int NXg = gridDim.x;
    const int T   = NXg * gridDim.y;
    int f = blockIdx.y * NXg + blockIdx.x;
    if ((T & 7) == 0) f = (f & 7) * (T >> 3) + (f >> 3);
    const int row0 = (f / NXg) * 128;
    const int col0 = (f % NXg) * 256;

    f32x4 acc[4][4];
    #pragma unroll
    for (int m = 0; m < 4; m++)
        #pragma unroll
        for (int n = 0; n < 4; n++)
            acc[m][n] = (f32x4){0.f, 0.f, 0.f, 0.f};

    // staging: unit = wid*64 + lane; row = unit>>2; chunk pre-swizzled
    const int rU = wid*16 + (lane >> 2);                    // 0..127
    const int ch = ((lane & 3) ^ ((lane >> 3) & 3)) * 8;    // swizzled chunk
    const bf16* pA  = A  + (size_t)(row0 + rU)*K + ch;
    const bf16* pB1 = Wb + (size_t)(col0 + rU)*K + ch;        // W rows col0..+127
    const bf16* pB2 = Wb + (size_t)(col0 + 128 + rU)*K + ch;  // W rows col0+128..+255

    #define STAGE(bi) { unsigned short* As_ = Sh + (bi)*12288;                 \
                        unsigned short* Bs_ = As_ + 4096;                      \
                        gl16(pA,  &As_[wid*512]);                              \
                        gl16(pB1, &Bs_[wid*512]);                              \
                        gl16(pB2, &Bs_[4096 + wid*512]);                       \
                        pA += 32; pB1 += 32; pB2 += 32; }

    #define COMPUTE(bi) { const unsigned short* As_ = Sh + (bi)*12288;         \
                          const unsigned short* Bs_ = As_ + 4096;              \
                          short8 af[4], bfr[4];                                \
                          _Pragma("unroll")                                    \
                          for (int m = 0; m < 4; m++)                          \
                              af[m] = *(const short8*)(&As_[(wr*64 + m*16 + l15)*32 + (quad ^ sw)*8]); \
                          _Pragma("unroll")                                    \
                          for (int n = 0; n < 4; n++)                          \
                              bfr[n] = *(const short8*)(&Bs_[(wc*64 + n*16 + l15)*32 + (quad ^ sw)*8]); \
                          _Pragma("unroll")                                    \
                          for (int m = 0; m < 4; m++)                          \
                              _Pragma("unroll")                                \
                              for (int n = 0; n < 4; n++)                      \
                                  acc[m][n] = __builtin_amdgcn_mfma_f32_16x16x32_bf16(af[m], bfr[n], acc[m][n], 0, 0, 0); }

    const int nt = K >> 5;                      // 8 (wo/fc1) or 32 (fc2)
    STAGE(0);
    int cur = 0;
    for (int t = 0; t < nt; t++) {
        if (t < nt - 1) {
            STAGE(cur ^ 1);
            asm volatile("s_waitcnt vmcnt(3)" ::: "memory");
        } else {
            asm volatile("s_waitcnt vmcnt(0)" ::: "memory");
        }
        __builtin_amdgcn_s_barrier();
        COMPUTE(cur);
        if (t < nt - 1) __builtin_amdgcn_s_barrier();
        cur ^= 1;
    }
    #undef STAGE
    #undef COMPUTE

    // ---- epilogue ----
    __syncthreads();
    float* Ls = (float*)Sh;                  // 8 waves x 1088 floats = 34816B
    float* SL = Ls + 8*1088;                 // 128 rows x 8 floats = 4KB
    const int cbl = l15 * 4;
    float4 stash[4][4];

    #pragma unroll
    for (int m = 0; m < 4; m++) {
        #pragma unroll
        for (int n = 0; n < 4; n++) {
            const float bval = bias[col0 + wc*64 + n*16 + l15];
            const int col = n*16 + l15;
            #pragma unroll
            for (int reg = 0; reg < 4; reg++) {
                float y = acc[m][n][reg] + bval;
                if (EPI == 0) y = gelu_fast(y);
                Ls[wid*1088 + (quad*4+reg)*68 + col] = y;
            }
        }
        #pragma unroll
        for (int p = 0; p < 4; p++) {
            const int rowt = p*4 + quad;
            const float4 v = *(const float4*)&Ls[wid*1088 + rowt*68 + cbl];
            const int rl = wr*64 + m*16 + rowt;
            if (EPI == 0) {
                const size_t o = (size_t)(row0 + rl) * N + col0 + wc*64 + cbl;
                uint2 ov; ov.x = pk2(v.x, v.y); ov.y = pk2(v.z, v.w);
                *(uint2*)(outB + o) = ov;
            } else {
                const size_t o = (size_t)(row0 + rl) * 256 + wc*64 + cbl;
                const float4 rv = *(const float4*)(residF + o);
                float4 w; w.x = v.x+rv.x; w.y = v.y+rv.y; w.z = v.z+rv.z; w.w = v.w+rv.w;
                *(float4*)(accF + o) = w;
                if (EPI == 1) {
                    stash[m][p] = w;
                    float ls1 = w.x + w.y + w.z + w.w;
                    float ls2 = w.x*w.x + w.y*w.y + w.z*w.z + w.w*w.w;
                    #pragma unroll
                    for (int d = 1; d < 16; d <<= 1) {
                        ls1 += __shfl_xor(ls1, d);
                        ls2 += __shfl_xor(ls2, d);
                    }
                    if (l15 == 0) { SL[rl*8 + wc*2] = ls1; SL[rl*8 + wc*2 + 1] = ls2; }
                }
            }
        }
    }
    if (EPI == 1) {
        __syncthreads();
        if (tid < 128) {
            const int row = tid;
            const float s1 = SL[row*8] + SL[row*8+2] + SL[row*8+4] + SL[row*8+6];
            const float s2 = SL[row*8+1] + SL[row*8+3] + SL[row*8+5] + SL[row*8+7];
            const float mu  = s1 * (1.0f/256.0f);
            const float var = s2 * (1.0f/256.0f) - mu*mu;
            SL[row*8]   = mu;
            SL[row*8+1] = rsqrtf(var + 1e-6f);
        }
        __syncthreads();
        const float4 g4 = *(const float4*)(g   + wc*64 + cbl);
        const float4 b4 = *(const float4*)(bln + wc*64 + cbl);
        #pragma unroll
        for (int m = 0; m < 4; m++) {
            #pragma unroll
            for (int p = 0; p < 4; p++) {
                const int rl = wr*64 + m*16 + p*4 + quad;
                const float mu  = SL[rl*8];
                const float inv = SL[rl*8+1];
                const float4 w = stash[m][p];
                uint2 ov;
                ov.x = pk2((w.x-mu)*inv*g4.x + b4.x, (w.y-mu)*inv*g4.y + b4.y);
                ov.y = pk2((w.z-mu)*inv*g4.z + b4.z, (w.w-mu)*inv*g4.w + b4.w);
                *(uint2*)(outB + (size_t)(row0 + rl)*256 + wc*64 + cbl) = ov;
            }
        }
    }
}

// ---- MFMA decomposed attention, in-register softmax, setprio'd MFMA. ----
template<bool COLM>
__global__ __launch_bounds__(256) void attn_mfma_kernel(
    const bf16* __restrict__ q, const bf16* __restrict__ k,
    const bf16* __restrict__ v, const bf16* __restrict__ lepe,
    bf16* __restrict__ outp)
{
    __shared__ unsigned short Qb[64*40];
    __shared__ unsigned short Kb[64*40];
    __shared__ unsigned short Vt[32*80];
    __shared__ unsigned short Pb[64*72];

    const int bid  = blockIdx.x;
    const int line = bid % 56;
    const int nh   = (bid / 56) % NHEAD;
    const int b    = bid / (56 * NHEAD);
    const int tid  = threadIdx.x;
    const int wid  = tid >> 6;
    const int lane = tid & 63;
    const int quad = lane >> 4;
    const int l15  = lane & 15;

    const size_t rstr = COLM ? (size_t)WWD * DD : (size_t)DD;
    const size_t base = COLM ? (((size_t)b*HH*WWD + line) * DD + nh*KDIM)
                             : (((size_t)(b*HH + line) * WWD) * DD + nh*KDIM);

    {
        const int r  = tid >> 2;
        const int cc = tid & 3;
        uint4 zero = {0,0,0,0};
        if (r < 56) {
            size_t gg = base + (size_t)r * rstr + cc*8;
            *(uint4*)(&Qb[r*40 + cc*8]) = *(const uint4*)(q + gg);
            *(uint4*)(&Kb[r*40 + cc*8]) = *(const uint4*)(k + gg);
        } else {
            *(uint4*)(&Qb[r*40 + cc*8]) = zero;
            *(uint4*)(&Kb[r*40 + cc*8]) = zero;
        }
        uint4 vv = zero;
        if (lane < 56)
            vv = *(const uint4*)(v + base + (size_t)lane * rstr + wid*8);
        const unsigned short* pv = (const unsigned short*)&vv;
        #pragma unroll
        for (int e = 0; e < 8; e++)
            Vt[(wid*8 + e)*80 + lane] = pv[e];
    }
    __syncthreads();

    {
        short8 af = *(const short8*)(&Qb[(wid*16 + l15)*40 + quad*8]);
        f32x4 s_[4];
        __builtin_amdgcn_s_setprio(1);
        #pragma unroll
        for (int j = 0; j < 4; j++) {
            short8 bfm = *(const short8*)(&Kb[(j*16 + l15)*40 + quad*8]);
            f32x4 z = {0.f,0.f,0.f,0.f};
            s_[j] = __builtin_amdgcn_mfma_f32_16x16x32_bf16(af, bfm, z, 0, 0, 0);
        }
        __builtin_amdgcn_s_setprio(0);
        const bool v3 = (l15 < 8);
        float mx[4], sm[4];
        #pragma unroll
        for (int reg = 0; reg < 4; reg++) {
            float m01 = fmaxf(s_[0][reg], s_[1][reg]);
            float m23 = v3 ? fmaxf(s_[2][reg], s_[3][reg]) : s_[2][reg];
            mx[reg] = fmaxf(m01, m23);
        }
        #pragma unroll
        for (int d = 1; d < 16; d <<= 1) {
            #pragma unroll
            for (int reg = 0; reg < 4; reg++)
                mx[reg] = fmaxf(mx[reg], __shfl_xor(mx[reg], d));
        }
        float e_[4][4];
        #pragma unroll
        for (int reg = 0; reg < 4; reg++) sm[reg] = 0.f;
        #pragma unroll
        for (int j = 0; j < 4; j++) {
            #pragma unroll
            for (int reg = 0; reg < 4; reg++) {
                const bool valid = (j < 3) || v3;
                float ex = valid ? expf(s_[j][reg] - mx[reg]) : 0.f;
                e_[j][reg] = ex;
                sm[reg] += ex;
            }
        }
        #pragma unroll
        for (int d = 1; d < 16; d <<= 1) {
            #pragma unroll
            for (int reg = 0; reg < 4; reg++)
                sm[reg] += __shfl_xor(sm[reg], d);
        }
        float inv[4];
        #pragma unroll
        for (int reg = 0; reg < 4; reg++) inv[reg] = 1.0f / sm[reg];
        #pragma unroll
        for (int j = 0; j < 4; j++)
            #pragma unroll
            for (int reg = 0; reg < 4; reg++)
                Pb[(wid*16 + quad*4 + reg)*72 + j*16 + l15] = f2bu(e_[j][reg] * inv[reg]);
    }
    __syncthreads();

    {
        f32x4 acc[2];
        acc[0] = (f32x4){0.f,0.f,0.f,0.f};
        acc[1] = (f32x4){0.f,0.f,0.f,0.f};
        __builtin_amdgcn_s_setprio(1);
        #pragma unroll
        for (int k0 = 0; k0 < 64; k0 += 32) {
            short8 af = *(const short8*)(&Pb[(wid*16 + l15)*72 + k0 + quad*8]);
            #pragma unroll
            for (int nt = 0; nt < 2; nt++) {
                short8 bfm = *(const short8*)(&Vt[(nt*16 + l15)*80 + k0 + quad*8]);
                acc[nt] = __builtin_amdgcn_mfma_f32_16x16x32_bf16(af, bfm, acc[nt], 0, 0, 0);
            }
        }
        __builtin_amdgcn_s_setprio(0);
        #pragma unroll
        for (int nt = 0; nt < 2; nt++) {
            #pragma unroll
            for (int reg = 0; reg < 4; reg++) {
                const int m = wid*16 + quad*4 + reg;
                const int d = nt*16 + l15;
                if (m < 56) {
                    float val = acc[nt][reg];
                    if (COLM) {
                        int hp = 7*nh + (m >> 3);
                        int wp = (m & 7)*7 + (line >> 3);
                        int cp = (line & 7)*32 + d;
                        size_t o = ((size_t)(b*HH + hp)*WWD + wp)*DD + cp;
                        outp[o] = __float2bfloat16(val + toF(lepe[o]));
                    } else {
                        outp[base + (size_t)m * rstr + d] = __float2bfloat16(val);
                    }
                }
            }
        }
    }
}

extern "C" void kernel_launch(void* const* d_in, const int* in_sizes, int n_in,
                              void* d_out, int out_size, void* d_ws, size_t ws_size,
                              hipStream_t stream)
{
    const float* x_in   = (const float*)d_in[0];
    const float* cpe_w  = (const float*)d_in[1];
    const float* cpe_b  = (const float*)d_in[2];
    const float* ln1_g  = (const float*)d_in[3];
    const float* ln1_b  = (const float*)d_in[4];
    const float* wq     = (const float*)d_in[5];
    const float* bq     = (const float*)d_in[6];
    const float* wk     = (const float*)d_in[7];
    const float* bk     = (const float*)d_in[8];
    const float* wv     = (const float*)d_in[9];
    const float* bv     = (const float*)d_in[10];
    const float* lepe_w = (const float*)d_in[11];
    const float* lepe_b = (const float*)d_in[12];
    const float* wo     = (const float*)d_in[13];
    const float* bo     = (const float*)d_in[14];
    const float* ln2_g  = (const float*)d_in[15];
    const float* ln2_b  = (const float*)d_in[16];
    const float* fc1_w  = (const float*)d_in[17];
    const float* fc1_b  = (const float*)d_in[18];
    const float* dw_w   = (const float*)d_in[19];
    const float* dw_b   = (const float*)d_in[20];
    const float* fc2_w  = (const float*)d_in[21];
    const float* fc2_b  = (const float*)d_in[22];
    float* out = (float*)d_out;

    const size_t ND = (size_t)NPIX * DD;
    const size_t NF = (size_t)NPIX * FFND;          // 4*ND
    char* ws = (char*)d_ws;
    float*  X0    = (float*)(ws);                          // ND fp32
    float*  ACC   = (float*)(ws + ND*4);                   // ND fp32
    bf16*   B1    = (bf16*) (ws + ND*8);                   // ND bf16 (xn1 / lepe)
    bf16*   B2    = (bf16*) (ws + ND*8 + ND*2);            // ND bf16 (q / xn2)
    bf16*   H1    = (bf16*) (ws + ND*8 + ND*4);            // NF bf16 (k alias / fc1 out)
    bf16*   H2    = (bf16*) (ws + ND*8 + ND*4 + NF*2);     // NF bf16 (v alias / dw out)
    bf16*   WB    = (bf16*) (ws + ND*8 + ND*4 + NF*4);     // 786432 bf16 weights
    float2* ROPET = (float2*)(ws + ND*8 + ND*4 + NF*4 + 786432*2); // 50176 float2
    float*  BQKV  = (float*) (ws + ND*8 + ND*4 + NF*4 + 786432*2 + 50176*8); // 768 f32
    bf16*   B3 = H1;                    // k (dead before fc1 writes)
    bf16*   B4 = H2;                    // v (dead before dw writes)
    bf16*   VWb   = (bf16*)d_out;       // d_out lo half: vw scratch
    bf16*   ATTNb = VWb + ND;           // d_out hi half: attn scrambled scratch

    const bf16* WOb = WB + 196608;
    const bf16* F1b = WB + 262144;
    const bf16* F2b = WB + 524288;

    dim3 b256(256);
    dim3 gridQKV(768/128, NPIX/128); // (6, 196)  T=1176

    // 0. one-shot init: bf16 weights + rope table + concat qkv bias (1 launch)
    init_kernel<<<583, b256, 0, stream>>>(wq, wk, wv, wo, fc1_w, fc2_w,
                                          bq, bk, bv, WB, ROPET, BQKV);
    // 1. CPE + LN1 fused (sliding window): X0 = x + dwconv3x3(x); B1 = LN(X0)
    cpe_ln_slide_kernel<<<NPIX/16, b256, 0, stream>>>(x_in, cpe_w, cpe_b, ln1_g, ln1_b, X0, B1);
    // 2. fused QKV projection (N=768 concat weights); rope on q,k; scale on k
    mgemm128_kernel<3,1><<<gridQKV, b256, 0, stream>>>(B1, WB, DD, BQKV, ROPET,
                                                       B2, B3, B4, NPIX, 768, DD, SCALE_K);
    // 3. LEPE: B1 = dwconv5x5(v)
    dwconv_slide_kernel<5, false, 256><<<784, b256, 0, stream>>>(B4, lepe_w, DD, lepe_b, B1);
    // 4. Row attention: (q,k,v) -> vw
    attn_mfma_kernel<false><<<HB*NHEAD*HH, b256, 0, stream>>>(B2, B3, B4, nullptr, VWb);
    // 5. Column attention; scrambled write + lepe -> ATTNb
    attn_mfma_kernel<true><<<HB*NHEAD*WWD, b256, 0, stream>>>(B2, B3, VWb, B1, ATTNb);
    // 6. WO projection + residual + LN2 fused: ACC = X0 + ATTNb*wo^T + bo; B2 = LN(ACC)
    mgemm_wide_kernel<1><<<dim3(1,196), dim3(512), 0, stream>>>(ATTNb, WOb, bo, X0, ACC,
                                                                ln2_g, ln2_b, B2, 256, 256);
    // 7. fc1 (128x256 wide tiles, N=1024) + fast GELU -> H1
    mgemm_wide_kernel<0><<<dim3(4,196), dim3(512), 0, stream>>>(B2, F1b, fc1_b, nullptr,
                                                                nullptr, nullptr, nullptr,
                                                                H1, 256, 1024);
    // 8. dwconv3x3 over 1024 channels + identity -> H2
    dwconv_slide_kernel<3, true, 1024><<<3136, b256, 0, stream>>>(H1, dw_w, FFND, dw_b, H2);
    // 9. fc2 (K=1024, 128x256 wide tile) + residual: out = ACC + H2*fc2^T + b
    mgemm_wide_kernel<2><<<dim3(1,196), dim3(512), 0, stream>>>(H2, F2b, fc2_b, ACC, out,
                                                                nullptr, nullptr, nullptr,
                                                                1024, 256);
}

// Round 14
// 315.798 us; speedup vs baseline: 1.0341x; 1.0341x over previous
//
#include <hip/hip_runtime.h>
#include <hip/hip_bf16.h>
#include <math.h>

typedef __hip_bfloat16 bf16;

#define HB 8
#define HH 56
#define WWD 56
#define DD 256
#define NHEAD 8
#define KDIM 32
#define FFND 1024
#define NPIX (HB*HH*WWD)             /* 25088 */
#define SCALE_K 0.17677669529663687f /* 32^-0.5 */

typedef __attribute__((ext_vector_type(8))) short short8;   // 8 bf16 (4 VGPRs)
typedef __attribute__((ext_vector_type(4))) float f32x4;

__device__ inline float toF(float x){ return x; }
__device__ inline float toF(bf16 x){ return __bfloat162float(x); }

__device__ inline float bfu_to_f(unsigned short u){
    union { float f; unsigned u32; } cv; cv.u32 = (unsigned)u << 16; return cv.f;
}

__device__ inline unsigned short f2bu(float f){
    union { bf16 b; unsigned short u; } cv; cv.b = __float2bfloat16(f); return cv.u;
}
__device__ inline unsigned pk2(float a, float b){
    return (unsigned)f2bu(a) | ((unsigned)f2bu(b) << 16);
}

// fast GELU: 0.5*y*(1+tanh(0.79788456*(y+0.044715*y^3))) = y*sigmoid(2u)
__device__ inline float gelu_fast(float y){
    const float u2 = y*y;
    const float arg = y * (2.302208219f + 0.1029402445f*u2);
    const float e2 = exp2f(fminf(arg, 126.0f));
    return y * e2 / (e2 + 1.0f);
}

// async global->LDS, 16B per lane; dest = wave-uniform base + lane*16 (HW adds it)
__device__ inline void gl16(const bf16* g, unsigned short* l){
    __builtin_amdgcn_global_load_lds((const __attribute__((address_space(1))) void*)g,
                                     (__attribute__((address_space(3))) void*)l, 16, 0, 0);
}

// ---- one-shot init: bf16 weights + rope table + concat qkv bias ----
__global__ __launch_bounds__(256) void init_kernel(
    const float* __restrict__ wq, const float* __restrict__ wk,
    const float* __restrict__ wv, const float* __restrict__ wo,
    const float* __restrict__ f1, const float* __restrict__ f2,
    const float* __restrict__ bq, const float* __restrict__ bk,
    const float* __restrict__ bv,
    bf16* __restrict__ dst, float2* __restrict__ ropet, float* __restrict__ bqkv)
{
    const int id = blockIdx.x*256 + threadIdx.x;   // 149248 total
    if (id < 98304) {
        const float* src; int off;
        if      (id < 8192)  { src = wq; off = id; }
        else if (id < 16384) { src = wk; off = id - 8192; }
        else if (id < 24576) { src = wv; off = id - 16384; }
        else if (id < 32768) { src = wo; off = id - 24576; }
        else if (id < 65536) { src = f1; off = id - 32768; }
        else                 { src = f2; off = id - 65536; }
        const float4 a = *(const float4*)(src + (size_t)off*8);
        const float4 b = *(const float4*)(src + (size_t)off*8 + 4);
        uint4 v; v.x = pk2(a.x,a.y); v.y = pk2(a.z,a.w); v.z = pk2(b.x,b.y); v.w = pk2(b.z,b.w);
        *(uint4*)(dst + (size_t)id*8) = v;
    } else if (id < 148480) {
        const int rid = id - 98304;                // 50176 rope entries
        const int idx = rid >> 4, i = rid & 15;
        const float ph = (float)idx * exp2f(-(float)i * 0.88584749196996324f);
        ropet[rid] = make_float2(cosf(ph), sinf(ph));
    } else {
        const int b = id - 148480;                 // 768 bias
        bqkv[b] = (b < 256) ? bq[b] : ((b < 512) ? bk[b-256] : bv[b-512]);
    }
}

// ---- CPE + LN1 fused, sliding-window ----
__global__ __launch_bounds__(256) void cpe_ln_slide_kernel(
    const float* __restrict__ x, const float* __restrict__ wt,
    const float* __restrict__ bias, const float* __restrict__ g,
    const float* __restrict__ bln, float* __restrict__ X0, bf16* __restrict__ B1)
{
    constexpr int C = 256, VEC = 4, NPX = 4, KS = 3, P = 1, NX = NPX + KS - 1;
    constexpr int GPR = WWD / NPX;          // 14 groups per row
    constexpr int NB  = NPIX / (NPX * 4);   // 1568 blocks
    const int tid  = threadIdx.x;
    const int wv   = tid >> 6;
    const int lane = tid & 63;
    const int bid  = blockIdx.x;
    const int swb  = (bid & 7) * (NB >> 3) + (bid >> 3);   // XCD-chunked
    const int gid  = swb * 4 + wv;
    const int row  = gid / GPR;             // 0..447 (b*56 + h)
    const int w0   = (gid % GPR) * NPX;
    const int h    = row % HH;
    const int b    = row / HH;
    const int c0   = lane * VEC;

    float acc[NPX][VEC];
    {
        const float4 b0 = *(const float4*)(bias + c0);
        #pragma unroll
        for (int j = 0; j < NPX; j++) {
            acc[j][0] = b0.x; acc[j][1] = b0.y; acc[j][2] = b0.z; acc[j][3] = b0.w;
        }
    }

    #pragma unroll
    for (int ky = 0; ky < KS; ky++) {
        const int hh = h + ky - P;
        if (hh < 0 || hh >= HH) continue;
        const float* rowp = x + ((size_t)(b*HH + hh) * WWD) * C + c0;
        float wvv[KS][VEC];
        #pragma unroll
        for (int kx = 0; kx < KS; kx++) {
            const float4 w4 = *(const float4*)(wt + (size_t)(ky*KS + kx)*C + c0);
            wvv[kx][0] = w4.x; wvv[kx][1] = w4.y; wvv[kx][2] = w4.z; wvv[kx][3] = w4.w;
        }
        #pragma unroll
        for (int xc = 0; xc < NX; xc++) {
            const int ww = w0 - P + xc;
            float4 f0 = {0.f, 0.f, 0.f, 0.f};
            if (ww >= 0 && ww < WWD) f0 = *(const float4*)(rowp + (size_t)ww*C);
            const float fv[VEC] = {f0.x, f0.y, f0.z, f0.w};
            #pragma unroll
            for (int j = 0; j < NPX; j++) {
                const int kx = xc - j;
                if (kx < 0 || kx >= KS) continue;
                #pragma unroll
                for (int e = 0; e < VEC; e++)
                    acc[j][e] += fv[e] * wvv[kx][e];
            }
        }
    }

    const float4 gv = *(const float4*)(g + c0);
    const float4 bv = *(const float4*)(bln + c0);
    #pragma unroll
    for (int j = 0; j < NPX; j++) {
        const size_t obase = ((size_t)row*WWD + w0 + j)*C + c0;
        {   // + input (residual trunk)
            const float4 r0 = *(const float4*)(x + obase);
            acc[j][0] += r0.x; acc[j][1] += r0.y; acc[j][2] += r0.z; acc[j][3] += r0.w;
        }
        { float4 o; o.x = acc[j][0]; o.y = acc[j][1]; o.z = acc[j][2]; o.w = acc[j][3];
          *(float4*)(X0 + obase) = o; }
        float s1 = acc[j][0] + acc[j][1] + acc[j][2] + acc[j][3];
        float s2 = acc[j][0]*acc[j][0] + acc[j][1]*acc[j][1]
                 + acc[j][2]*acc[j][2] + acc[j][3]*acc[j][3];
        #pragma unroll
        for (int d = 1; d < 64; d <<= 1) { s1 += __shfl_xor(s1, d); s2 += __shfl_xor(s2, d); }
        const float mu  = s1 * (1.0f/DD);
        const float var = s2 * (1.0f/DD) - mu*mu;
        const float inv = rsqrtf(var + 1e-6f);
        uint2 o2;
        o2.x = pk2((acc[j][0]-mu)*inv*gv.x + bv.x, (acc[j][1]-mu)*inv*gv.y + bv.y);
        o2.y = pk2((acc[j][2]-mu)*inv*gv.z + bv.z, (acc[j][3]-mu)*inv*gv.w + bv.w);
        *(uint2*)(B1 + obase) = o2;
    }
}

// ---- sliding-window depthwise conv, bf16, VEC=8 ch/thread, 4 px/thread. ----
template<int KS, bool ADD, int C>
__global__ __launch_bounds__(256) void dwconv_slide_kernel(
    const bf16* __restrict__ in, const float* __restrict__ wt, int wst,
    const float* __restrict__ bias, bf16* __restrict__ out)
{
    constexpr int VEC = 8, CG = C/VEC, GPB = 256/CG, NPX = 4, P = KS/2, NX = NPX+KS-1;
    constexpr int GPR = WWD/NPX;          // 14 groups per row
    constexpr int NB  = NPIX/(NPX*GPB);   // grid size
    const int tid = threadIdx.x;
    const int cg  = tid % CG;
    const int gl  = tid / CG;
    const int bid = blockIdx.x;
    const int swb = (bid & 7) * (NB >> 3) + (bid >> 3);   // XCD-chunked
    const int gid = swb * GPB + gl;
    const int row = gid / GPR;            // 0..447 (b*56 + h)
    const int w0  = (gid % GPR) * NPX;
    const int h   = row % HH;
    const int b   = row / HH;
    const int c0  = cg * VEC;

    float acc[NPX][VEC];
    {
        const float4 b0 = *(const float4*)(bias + c0);
        const float4 b1 = *(const float4*)(bias + c0 + 4);
        #pragma unroll
        for (int j = 0; j < NPX; j++) {
            acc[j][0]=b0.x; acc[j][1]=b0.y; acc[j][2]=b0.z; acc[j][3]=b0.w;
            acc[j][4]=b1.x; acc[j][5]=b1.y; acc[j][6]=b1.z; acc[j][7]=b1.w;
        }
    }

    #pragma unroll
    for (int ky = 0; ky < KS; ky++) {
        const int hh = h + ky - P;
        if (hh < 0 || hh >= HH) continue;
        const bf16* rowp = in + ((size_t)(b*HH + hh) * WWD) * C + c0;
        float wv[KS][VEC];
        #pragma unroll
        for (int kx = 0; kx < KS; kx++) {
            const float* wp = wt + (size_t)(ky*KS + kx)*wst + c0;
            const float4 w0v = *(const float4*)(wp);
            const float4 w1v = *(const float4*)(wp + 4);
            wv[kx][0]=w0v.x; wv[kx][1]=w0v.y; wv[kx][2]=w0v.z; wv[kx][3]=w0v.w;
            wv[kx][4]=w1v.x; wv[kx][5]=w1v.y; wv[kx][6]=w1v.z; wv[kx][7]=w1v.w;
        }
        #pragma unroll
        for (int x = 0; x < NX; x++) {
            const int ww = w0 - P + x;
            short8 raw = {0,0,0,0,0,0,0,0};
            if (ww >= 0 && ww < WWD) raw = *(const short8*)(rowp + (size_t)ww*C);
            float f[VEC];
            #pragma unroll
            for (int e = 0; e < VEC; e++) f[e] = bfu_to_f((unsigned short)raw[e]);
            #pragma unroll
            for (int j = 0; j < NPX; j++) {
                const int kx = x - j;
                if (kx < 0 || kx >= KS) continue;
                #pragma unroll
                for (int e = 0; e < VEC; e++)
                    acc[j][e] += f[e] * wv[kx][e];
            }
        }
    }

    #pragma unroll
    for (int j = 0; j < NPX; j++) {
        const size_t obase = ((size_t)row*WWD + w0 + j)*C + c0;
        if constexpr (ADD) {
            short8 vv = *(const short8*)(in + obase);
            #pragma unroll
            for (int e = 0; e < VEC; e++) acc[j][e] += bfu_to_f((unsigned short)vv[e]);
        }
        uint4 o;
        o.x = pk2(acc[j][0], acc[j][1]); o.y = pk2(acc[j][2], acc[j][3]);
        o.z = pk2(acc[j][4], acc[j][5]); o.w = pk2(acc[j][6], acc[j][7]);
        *(uint4*)(out + obase) = o;
    }
}

// ---- MFMA GEMM: 128x128 tile, 4 waves (2x2), acc[4][4], BK=32, bf16 weights.
// Depth-2 pipeline (3 LDS buffers, gl16, counted vmcnt) + T2 swizzle.
// EPI: 0 = bf16 out, 1 = fast-GELU bf16 out, 2 = fp32 resid+out,
//      3 = QKV fused (N=768 concat weights; seg 0=q(rope),1=k(rope+scale),2=v).
template<int EPI, int ROPE>
__global__ __launch_bounds__(256) void mgemm128_kernel(
    const bf16* __restrict__ A, const bf16* __restrict__ Wb, int ldw,
    const float* __restrict__ bias, const float2* __restrict__ ropet,
    const float* __restrict__ residF, float* __restrict__ accF,
    bf16* __restrict__ outB, bf16* __restrict__ outK, bf16* __restrict__ outV,
    int M, int N, int K, float scale)
{
    __shared__ __align__(16) unsigned short Sh[24576];  // 48KB: 3 x (As 8KB | Bs 8KB)
    const int tid  = threadIdx.x;
    const int wid  = tid >> 6;
    const int lane = tid & 63;
    const int quad = lane >> 4;
    const int l15  = lane & 15;
    const int wr   = wid >> 1;
    const int wc   = wid & 1;
    const int sw   = (l15 >> 1) & 3;     // frag-read chunk swizzle (= (row>>1)&3)

    // XCD-chunked tile swizzle (T divisible by 8)
    const int NXg = gridDim.x;
    const int T   = NXg * gridDim.y;
    int f = blockIdx.y * NXg + blockIdx.x;
    f = (f & 7) * (T >> 3) + (f >> 3);
    const int row0 = (f / NXg) * 128;
    const int col0 = (f % NXg) * 128;

    f32x4 acc[4][4];
    #pragma unroll
    for (int m = 0; m < 4; m++)
        #pragma unroll
        for (int n = 0; n < 4; n++)
            acc[m][n] = (f32x4){0.f, 0.f, 0.f, 0.f};

    // staging source pointers; chunk pre-swizzled so LDS[row][s] holds
    // global chunk s^((row>>1)&3)  (unit o: row=o>>2, slot=o&3)
    const int ob0 = (wid*2 + 0)*64;          // wave-uniform 16B-unit bases
    const int ob1 = (wid*2 + 1)*64;
    const int o0  = ob0 + lane, o1 = ob1 + lane;
    const int rA0 = o0 >> 2, ch0 = ((o0 & 3) ^ ((o0 >> 3) & 3)) * 8;
    const int rA1 = o1 >> 2, ch1 = ((o1 & 3) ^ ((o1 >> 3) & 3)) * 8;
    const bf16* pA0 = A  + (size_t)(row0 + rA0)*K   + ch0;
    const bf16* pA1 = A  + (size_t)(row0 + rA1)*K   + ch1;
    const bf16* pW0 = Wb + (size_t)(col0 + rA0)*ldw + ch0;
    const bf16* pW1 = Wb + (size_t)(col0 + rA1)*ldw + ch1;

    #define STAGE(bi) { unsigned short* As_ = Sh + (bi)*8192;                  \
                        unsigned short* Bs_ = As_ + 4096;                      \
                        gl16(pA0, &As_[ob0*8]); gl16(pA1, &As_[ob1*8]);        \
                        gl16(pW0, &Bs_[ob0*8]); gl16(pW1, &Bs_[ob1*8]);        \
                        pA0 += 32; pA1 += 32; pW0 += 32; pW1 += 32; }

    #define COMPUTE(bi) { const unsigned short* As_ = Sh + (bi)*8192;          \
                          const unsigned short* Bs_ = As_ + 4096;              \
                          short8 af[4], bfr[4];                                \
                          _Pragma("unroll")                                    \
                          for (int m = 0; m < 4; m++)                          \
                              af[m] = *(const short8*)(&As_[(wr*64 + m*16 + l15)*32 + (quad ^ sw)*8]); \
                          _Pragma("unroll")                                    \
                          for (int n = 0; n < 4; n++)                          \
                              bfr[n] = *(const short8*)(&Bs_[(wc*64 + n*16 + l15)*32 + (quad ^ sw)*8]); \
                          _Pragma("unroll")                                    \
                          for (int m = 0; m < 4; m++)                          \
                              _Pragma("unroll")                                \
                              for (int n = 0; n < 4; n++)                      \
                                  acc[m][n] = __builtin_amdgcn_mfma_f32_16x16x32_bf16(af[m], bfr[n], acc[m][n], 0, 0, 0); }

    const int nt = K >> 5;                      // 8 or 32, always >= 3
    STAGE(0); STAGE(1);                         // tiles 0,1 in flight
    int cur = 0;
    for (int t = 0; t < nt; t++) {
        if (t + 2 < nt) {
            const int nx = (cur == 0) ? 2 : ((cur == 1) ? 0 : 1);   // (cur+2)%3
            STAGE(nx);                          // tile t+2 -> third buf (in flight)
            asm volatile("s_waitcnt vmcnt(8)" ::: "memory");        // tile t landed
        } else if (t + 1 < nt) {
            asm volatile("s_waitcnt vmcnt(4)" ::: "memory");
        } else {
            asm volatile("s_waitcnt vmcnt(0)" ::: "memory");
        }
        __builtin_amdgcn_s_barrier();           // all waves' tile-t loads landed
        COMPUTE(cur);
        if (t + 1 < nt) __builtin_amdgcn_s_barrier();  // done reading before overwrite
        cur = (cur == 2) ? 0 : cur + 1;
    }
    #undef STAGE
    #undef COMPUTE

    // ---- epilogue: per-wave LDS transpose -> coalesced stores ----
    __syncthreads();
    float* Ls = (float*)Sh;                  // 4 waves x 16 x 68 floats = 17408B
    const int cbl = l15 * 4;
    const int seg = (EPI == 3) ? (col0 >> 8) : 0;
    bf16* dst = outB;
    if (EPI == 3) dst = (seg == 0) ? outB : ((seg == 1) ? outK : outV);
    const float esc = (EPI == 3) ? ((seg == 1) ? scale : 1.0f) : scale;
    const bool doRope = ROPE && (EPI != 3 || seg < 2);

    #pragma unroll
    for (int m = 0; m < 4; m++) {
        #pragma unroll
        for (int n = 0; n < 4; n++) {
            const int col = n*16 + l15;
            const float bval = bias[col0 + wc*64 + col];
            #pragma unroll
            for (int reg = 0; reg < 4; reg++) {
                float y = (acc[m][n][reg] + bval) * esc;
                if (EPI == 1) y = gelu_fast(y);
                Ls[wid*1088 + (quad*4+reg)*68 + col] = y;
            }
        }
        #pragma unroll
        for (int p = 0; p < 4; p++) {
            const int rowt = p*4 + quad;
            const float4 v = *(const float4*)&Ls[wid*1088 + rowt*68 + cbl];
            const int mm = row0 + wr*64 + m*16 + rowt;
            if (EPI == 2) {
                const size_t o = (size_t)mm * N + col0 + wc*64 + cbl;
                const float4 rv = *(const float4*)(residF + o);
                float4 w; w.x = v.x+rv.x; w.y = v.y+rv.y; w.z = v.z+rv.z; w.w = v.w+rv.w;
                *(float4*)(accF + o) = w;
            } else {
                const int ncl = (EPI == 3) ? ((col0 & 255) + wc*64 + cbl)
                                           : (col0 + wc*64 + cbl);
                const size_t o = (EPI == 3) ? ((size_t)mm * 256 + ncl)
                                            : ((size_t)mm * N + ncl);
                float a = v.x, b = v.y, c = v.z, d = v.w;
                if (doRope) {
                    const int idx = mm % (HH*WWD);
                    const int i0 = (ncl & 31) >> 1;   // even -> float4-aligned
                    const float4 t = *(const float4*)&ropet[(size_t)idx*16 + i0];
                    const float na  = a*t.x - b*t.y;
                    const float nb  = b*t.x + a*t.y;
                    const float ncv = c*t.z - d*t.w;
                    const float nd  = d*t.z + c*t.w;
                    a = na; b = nb; c = ncv; d = nd;
                }
                uint2 ov; ov.x = pk2(a, b); ov.y = pk2(c, d);
                *(uint2*)(dst + o) = ov;
            }
        }
    }
}

// ---- 512-thread 128x256-tile GEMM (N=256), K via arg. 8 waves (2 row x 4 col),
// depth-2 gl16 pipeline (3 x 24KB LDS buffers; grids here are <1 block/CU so
// in-block depth is the only latency cover), T2 swizzle. Epilogues:
// DOLN=1: WO+residual+LN2 (accF = x1, outB = LN(x1) bf16)
// DOLN=0: fc2+residual     (accF = residF + GEMM + bias, fp32 final out)
template<int DOLN>
__global__ __launch_bounds__(512) void mgemm_wide_kernel(
    const bf16* __restrict__ A, const bf16* __restrict__ Wb,
    const float* __restrict__ bias, const float* __restrict__ residF,
    float* __restrict__ accF, const float* __restrict__ g,
    const float* __restrict__ bln, bf16* __restrict__ outB, int K)
{
    __shared__ __align__(16) unsigned short Sh[36864];  // 72KB: 3 x (As 8KB | Bs 16KB)
    const int tid  = threadIdx.x;
    const int wid  = tid >> 6;          // 0..7
    const int lane = tid & 63;
    const int quad = lane >> 4;
    const int l15  = lane & 15;
    const int wr   = wid >> 2;          // 0..1  (64-row half)
    const int wc   = wid & 3;           // 0..3  (64-col quarter)
    const int sw   = (l15 >> 1) & 3;
    const int row0 = blockIdx.x * 128;

    f32x4 acc[4][4];
    #pragma unroll
    for (int m = 0; m < 4; m++)
        #pragma unroll
        for (int n = 0; n < 4; n++)
            acc[m][n] = (f32x4){0.f, 0.f, 0.f, 0.f};

    // staging: unit = wid*64 + lane; row = unit>>2; chunk pre-swizzled
    const int rU = wid*16 + (lane >> 2);                    // 0..127
    const int ch = ((lane & 3) ^ ((lane >> 3) & 3)) * 8;    // swizzled chunk
    const bf16* pA  = A  + (size_t)(row0 + rU)*K + ch;
    const bf16* pB1 = Wb + (size_t)rU*K + ch;               // W rows 0..127
    const bf16* pB2 = Wb + (size_t)(128 + rU)*K + ch;       // W rows 128..255

    #define STAGE(bi) { unsigned short* As_ = Sh + (bi)*12288;                 \
                        unsigned short* Bs_ = As_ + 4096;                      \
                        gl16(pA,  &As_[wid*512]);                              \
                        gl16(pB1, &Bs_[wid*512]);                              \
                        gl16(pB2, &Bs_[4096 + wid*512]);                       \
                        pA += 32; pB1 += 32; pB2 += 32; }

    #define COMPUTE(bi) { const unsigned short* As_ = Sh + (bi)*12288;         \
                          const unsigned short* Bs_ = As_ + 4096;              \
                          short8 af[4], bfr[4];                                \
                          _Pragma("unroll")                                    \
                          for (int m = 0; m < 4; m++)                          \
                              af[m] = *(const short8*)(&As_[(wr*64 + m*16 + l15)*32 + (quad ^ sw)*8]); \
                          _Pragma("unroll")                                    \
                          for (int n = 0; n < 4; n++)                          \
                              bfr[n] = *(const short8*)(&Bs_[(wc*64 + n*16 + l15)*32 + (quad ^ sw)*8]); \
                          _Pragma("unroll")                                    \
                          for (int m = 0; m < 4; m++)                          \
                              _Pragma("unroll")                                \
                              for (int n = 0; n < 4; n++)                      \
                                  acc[m][n] = __builtin_amdgcn_mfma_f32_16x16x32_bf16(af[m], bfr[n], acc[m][n], 0, 0, 0); }

    const int nt = K >> 5;                      // 8 (wo) or 32 (fc2), >= 3
    STAGE(0); STAGE(1);                         // tiles 0,1 in flight
    int cur = 0;
    for (int t = 0; t < nt; t++) {
        if (t + 2 < nt) {
            const int nx = (cur == 0) ? 2 : ((cur == 1) ? 0 : 1);   // (cur+2)%3
            STAGE(nx);                          // tile t+2 in flight
            asm volatile("s_waitcnt vmcnt(6)" ::: "memory");        // tile t landed
        } else if (t + 1 < nt) {
            asm volatile("s_waitcnt vmcnt(3)" ::: "memory");
        } else {
            asm volatile("s_waitcnt vmcnt(0)" ::: "memory");
        }
        __builtin_amdgcn_s_barrier();
        COMPUTE(cur);
        if (t + 1 < nt) __builtin_amdgcn_s_barrier();
        cur = (cur == 2) ? 0 : cur + 1;
    }
    #undef STAGE
    #undef COMPUTE

    // ---- epilogue ----
    __syncthreads();
    float* Ls = (float*)Sh;                  // 8 waves x 1088 floats = 34816B
    float* SL = Ls + 8*1088;                 // 128 rows x 8 floats = 4KB
    const int cbl = l15 * 4;
    float4 stash[4][4];

    #pragma unroll
    for (int m = 0; m < 4; m++) {
        #pragma unroll
        for (int n = 0; n < 4; n++) {
            const float bval = bias[wc*64 + n*16 + l15];
            const int col = n*16 + l15;
            #pragma unroll
            for (int reg = 0; reg < 4; reg++)
                Ls[wid*1088 + (quad*4+reg)*68 + col] = acc[m][n][reg] + bval;
        }
        #pragma unroll
        for (int p = 0; p < 4; p++) {
            const int rowt = p*4 + quad;
            const float4 v = *(const float4*)&Ls[wid*1088 + rowt*68 + cbl];
            const int rl = wr*64 + m*16 + rowt;
            const size_t o = (size_t)(row0 + rl) * 256 + wc*64 + cbl;
            const float4 rv = *(const float4*)(residF + o);
            float4 w; w.x = v.x+rv.x; w.y = v.y+rv.y; w.z = v.z+rv.z; w.w = v.w+rv.w;
            *(float4*)(accF + o) = w;
            if (DOLN) {
                stash[m][p] = w;
                float ls1 = w.x + w.y + w.z + w.w;
                float ls2 = w.x*w.x + w.y*w.y + w.z*w.z + w.w*w.w;
                #pragma unroll
                for (int d = 1; d < 16; d <<= 1) {
                    ls1 += __shfl_xor(ls1, d);
                    ls2 += __shfl_xor(ls2, d);
                }
                if (l15 == 0) { SL[rl*8 + wc*2] = ls1; SL[rl*8 + wc*2 + 1] = ls2; }
            }
        }
    }
    if (DOLN) {
        __syncthreads();
        if (tid < 128) {
            const int row = tid;
            const float s1 = SL[row*8] + SL[row*8+2] + SL[row*8+4] + SL[row*8+6];
            const float s2 = SL[row*8+1] + SL[row*8+3] + SL[row*8+5] + SL[row*8+7];
            const float mu  = s1 * (1.0f/256.0f);
            const float var = s2 * (1.0f/256.0f) - mu*mu;
            SL[row*8]   = mu;
            SL[row*8+1] = rsqrtf(var + 1e-6f);
        }
        __syncthreads();
        const float4 g4 = *(const float4*)(g   + wc*64 + cbl);
        const float4 b4 = *(const float4*)(bln + wc*64 + cbl);
        #pragma unroll
        for (int m = 0; m < 4; m++) {
            #pragma unroll
            for (int p = 0; p < 4; p++) {
                const int rl = wr*64 + m*16 + p*4 + quad;
                const float mu  = SL[rl*8];
                const float inv = SL[rl*8+1];
                const float4 w = stash[m][p];
                uint2 ov;
                ov.x = pk2((w.x-mu)*inv*g4.x + b4.x, (w.y-mu)*inv*g4.y + b4.y);
                ov.y = pk2((w.z-mu)*inv*g4.z + b4.z, (w.w-mu)*inv*g4.w + b4.w);
                *(uint2*)(outB + (size_t)(row0 + rl)*256 + wc*64 + cbl) = ov;
            }
        }
    }
}

// ---- MFMA decomposed attention, in-register softmax, setprio'd MFMA. ----
template<bool COLM>
__global__ __launch_bounds__(256) void attn_mfma_kernel(
    const bf16* __restrict__ q, const bf16* __restrict__ k,
    const bf16* __restrict__ v, const bf16* __restrict__ lepe,
    bf16* __restrict__ outp)
{
    __shared__ unsigned short Qb[64*40];
    __shared__ unsigned short Kb[64*40];
    __shared__ unsigned short Vt[32*80];
    __shared__ unsigned short Pb[64*72];

    const int bid  = blockIdx.x;
    const int line = bid % 56;
    const int nh   = (bid / 56) % NHEAD;
    const int b    = bid / (56 * NHEAD);
    const int tid  = threadIdx.x;
    const int wid  = tid >> 6;
    const int lane = tid & 63;
    const int quad = lane >> 4;
    const int l15  = lane & 15;

    const size_t rstr = COLM ? (size_t)WWD * DD : (size_t)DD;
    const size_t base = COLM ? (((size_t)b*HH*WWD + line) * DD + nh*KDIM)
                             : (((size_t)(b*HH + line) * WWD) * DD + nh*KDIM);

    {
        const int r  = tid >> 2;
        const int cc = tid & 3;
        uint4 zero = {0,0,0,0};
        if (r < 56) {
            size_t gg = base + (size_t)r * rstr + cc*8;
            *(uint4*)(&Qb[r*40 + cc*8]) = *(const uint4*)(q + gg);
            *(uint4*)(&Kb[r*40 + cc*8]) = *(const uint4*)(k + gg);
        } else {
            *(uint4*)(&Qb[r*40 + cc*8]) = zero;
            *(uint4*)(&Kb[r*40 + cc*8]) = zero;
        }
        uint4 vv = zero;
        if (lane < 56)
            vv = *(const uint4*)(v + base + (size_t)lane * rstr + wid*8);
        const unsigned short* pv = (const unsigned short*)&vv;
        #pragma unroll
        for (int e = 0; e < 8; e++)
            Vt[(wid*8 + e)*80 + lane] = pv[e];
    }
    __syncthreads();

    {
        short8 af = *(const short8*)(&Qb[(wid*16 + l15)*40 + quad*8]);
        f32x4 s_[4];
        __builtin_amdgcn_s_setprio(1);
        #pragma unroll
        for (int j = 0; j < 4; j++) {
            short8 bfm = *(const short8*)(&Kb[(j*16 + l15)*40 + quad*8]);
            f32x4 z = {0.f,0.f,0.f,0.f};
            s_[j] = __builtin_amdgcn_mfma_f32_16x16x32_bf16(af, bfm, z, 0, 0, 0);
        }
        __builtin_amdgcn_s_setprio(0);
        const bool v3 = (l15 < 8);
        float mx[4], sm[4];
        #pragma unroll
        for (int reg = 0; reg < 4; reg++) {
            float m01 = fmaxf(s_[0][reg], s_[1][reg]);
            float m23 = v3 ? fmaxf(s_[2][reg], s_[3][reg]) : s_[2][reg];
            mx[reg] = fmaxf(m01, m23);
        }
        #pragma unroll
        for (int d = 1; d < 16; d <<= 1) {
            #pragma unroll
            for (int reg = 0; reg < 4; reg++)
                mx[reg] = fmaxf(mx[reg], __shfl_xor(mx[reg], d));
        }
        float e_[4][4];
        #pragma unroll
        for (int reg = 0; reg < 4; reg++) sm[reg] = 0.f;
        #pragma unroll
        for (int j = 0; j < 4; j++) {
            #pragma unroll
            for (int reg = 0; reg < 4; reg++) {
                const bool valid = (j < 3) || v3;
                float ex = valid ? expf(s_[j][reg] - mx[reg]) : 0.f;
                e_[j][reg] = ex;
                sm[reg] += ex;
            }
        }
        #pragma unroll
        for (int d = 1; d < 16; d <<= 1) {
            #pragma unroll
            for (int reg = 0; reg < 4; reg++)
                sm[reg] += __shfl_xor(sm[reg], d);
        }
        float inv[4];
        #pragma unroll
        for (int reg = 0; reg < 4; reg++) inv[reg] = 1.0f / sm[reg];
        #pragma unroll
        for (int j = 0; j < 4; j++)
            #pragma unroll
            for (int reg = 0; reg < 4; reg++)
                Pb[(wid*16 + quad*4 + reg)*72 + j*16 + l15] = f2bu(e_[j][reg] * inv[reg]);
    }
    __syncthreads();

    {
        f32x4 acc[2];
        acc[0] = (f32x4){0.f,0.f,0.f,0.f};
        acc[1] = (f32x4){0.f,0.f,0.f,0.f};
        __builtin_amdgcn_s_setprio(1);
        #pragma unroll
        for (int k0 = 0; k0 < 64; k0 += 32) {
            short8 af = *(const short8*)(&Pb[(wid*16 + l15)*72 + k0 + quad*8]);
            #pragma unroll
            for (int nt = 0; nt < 2; nt++) {
                short8 bfm = *(const short8*)(&Vt[(nt*16 + l15)*80 + k0 + quad*8]);
                acc[nt] = __builtin_amdgcn_mfma_f32_16x16x32_bf16(af, bfm, acc[nt], 0, 0, 0);
            }
        }
        __builtin_amdgcn_s_setprio(0);
        #pragma unroll
        for (int nt = 0; nt < 2; nt++) {
            #pragma unroll
            for (int reg = 0; reg < 4; reg++) {
                const int m = wid*16 + quad*4 + reg;
                const int d = nt*16 + l15;
                if (m < 56) {
                    float val = acc[nt][reg];
                    if (COLM) {
                        int hp = 7*nh + (m >> 3);
                        int wp = (m & 7)*7 + (line >> 3);
                        int cp = (line & 7)*32 + d;
                        size_t o = ((size_t)(b*HH + hp)*WWD + wp)*DD + cp;
                        outp[o] = __float2bfloat16(val + toF(lepe[o]));
                    } else {
                        outp[base + (size_t)m * rstr + d] = __float2bfloat16(val);
                    }
                }
            }
        }
    }
}

extern "C" void kernel_launch(void* const* d_in, const int* in_sizes, int n_in,
                              void* d_out, int out_size, void* d_ws, size_t ws_size,
                              hipStream_t stream)
{
    const float* x_in   = (const float*)d_in[0];
    const float* cpe_w  = (const float*)d_in[1];
    const float* cpe_b  = (const float*)d_in[2];
    const float* ln1_g  = (const float*)d_in[3];
    const float* ln1_b  = (const float*)d_in[4];
    const float* wq     = (const float*)d_in[5];
    const float* bq     = (const float*)d_in[6];
    const float* wk     = (const float*)d_in[7];
    const float* bk     = (const float*)d_in[8];
    const float* wv     = (const float*)d_in[9];
    const float* bv     = (const float*)d_in[10];
    const float* lepe_w = (const float*)d_in[11];
    const float* lepe_b = (const float*)d_in[12];
    const float* wo     = (const float*)d_in[13];
    const float* bo     = (const float*)d_in[14];
    const float* ln2_g  = (const float*)d_in[15];
    const float* ln2_b  = (const float*)d_in[16];
    const float* fc1_w  = (const float*)d_in[17];
    const float* fc1_b  = (const float*)d_in[18];
    const float* dw_w   = (const float*)d_in[19];
    const float* dw_b   = (const float*)d_in[20];
    const float* fc2_w  = (const float*)d_in[21];
    const float* fc2_b  = (const float*)d_in[22];
    float* out = (float*)d_out;

    const size_t ND = (size_t)NPIX * DD;
    const size_t NF = (size_t)NPIX * FFND;          // 4*ND
    char* ws = (char*)d_ws;
    float*  X0    = (float*)(ws);                          // ND fp32
    float*  ACC   = (float*)(ws + ND*4);                   // ND fp32
    bf16*   B1    = (bf16*) (ws + ND*8);                   // ND bf16 (xn1 / lepe)
    bf16*   B2    = (bf16*) (ws + ND*8 + ND*2);            // ND bf16 (q / xn2)
    bf16*   H1    = (bf16*) (ws + ND*8 + ND*4);            // NF bf16 (k alias / fc1 out)
    bf16*   H2    = (bf16*) (ws + ND*8 + ND*4 + NF*2);     // NF bf16 (v alias / dw out)
    bf16*   WB    = (bf16*) (ws + ND*8 + ND*4 + NF*4);     // 786432 bf16 weights
    float2* ROPET = (float2*)(ws + ND*8 + ND*4 + NF*4 + 786432*2); // 50176 float2
    float*  BQKV  = (float*) (ws + ND*8 + ND*4 + NF*4 + 786432*2 + 50176*8); // 768 f32
    bf16*   B3 = H1;                    // k (dead before fc1 writes)
    bf16*   B4 = H2;                    // v (dead before dw writes)
    bf16*   VWb   = (bf16*)d_out;       // d_out lo half: vw scratch
    bf16*   ATTNb = VWb + ND;           // d_out hi half: attn scrambled scratch

    const bf16* WOb = WB + 196608;
    const bf16* F1b = WB + 262144;
    const bf16* F2b = WB + 524288;

    dim3 b256(256);
    dim3 gridQKV(768/128, NPIX/128); // (6, 196)  T=1176
    dim3 gridF(FFND/128, NPIX/128);  // (8, 196)  T=1568

    // 0. one-shot init: bf16 weights + rope table + concat qkv bias (1 launch)
    init_kernel<<<583, b256, 0, stream>>>(wq, wk, wv, wo, fc1_w, fc2_w,
                                          bq, bk, bv, WB, ROPET, BQKV);
    // 1. CPE + LN1 fused (sliding window): X0 = x + dwconv3x3(x); B1 = LN(X0)
    cpe_ln_slide_kernel<<<NPIX/16, b256, 0, stream>>>(x_in, cpe_w, cpe_b, ln1_g, ln1_b, X0, B1);
    // 2. fused QKV projection (N=768 concat weights); rope on q,k; scale on k
    mgemm128_kernel<3,1><<<gridQKV, b256, 0, stream>>>(B1, WB, DD, BQKV, ROPET,
                                                       nullptr, nullptr, B2, B3, B4,
                                                       NPIX, 768, DD, SCALE_K);
    // 3. LEPE: B1 = dwconv5x5(v)
    dwconv_slide_kernel<5, false, 256><<<784, b256, 0, stream>>>(B4, lepe_w, DD, lepe_b, B1);
    // 4. Row attention: (q,k,v) -> vw
    attn_mfma_kernel<false><<<HB*NHEAD*HH, b256, 0, stream>>>(B2, B3, B4, nullptr, VWb);
    // 5. Column attention; scrambled write + lepe -> ATTNb
    attn_mfma_kernel<true><<<HB*NHEAD*WWD, b256, 0, stream>>>(B2, B3, VWb, B1, ATTNb);
    // 6. WO projection + residual + LN2 fused: ACC = X0 + ATTNb*wo^T + bo; B2 = LN(ACC)
    mgemm_wide_kernel<1><<<196, dim3(512), 0, stream>>>(ATTNb, WOb, bo, X0, ACC,
                                                        ln2_g, ln2_b, B2, 256);
    // 7. fc1 (N=1024, 128x128 tiles, depth-2) + fast GELU -> H1
    mgemm128_kernel<1,0><<<gridF, b256, 0, stream>>>(B2, F1b, DD, fc1_b, nullptr,
                                                     nullptr, nullptr, H1, nullptr, nullptr,
                                                     NPIX, FFND, DD, 1.0f);
    // 8. dwconv3x3 over 1024 channels + identity -> H2
    dwconv_slide_kernel<3, true, 1024><<<3136, b256, 0, stream>>>(H1, dw_w, FFND, dw_b, H2);
    // 9. fc2 (K=1024, 128x256 wide tile, depth-2) + residual: out = ACC + H2*fc2^T + b
    mgemm_wide_kernel<0><<<196, dim3(512), 0, stream>>>(H2, F2b, fc2_b, ACC, out,
                                                        nullptr, nullptr, nullptr, 1024);
}

// Round 15
// 311.849 us; speedup vs baseline: 1.0472x; 1.0127x over previous
//
#include <hip/hip_runtime.h>
#include <hip/hip_bf16.h>
#include <math.h>

typedef __hip_bfloat16 bf16;

#define HB 8
#define HH 56
#define WWD 56
#define DD 256
#define NHEAD 8
#define KDIM 32
#define FFND 1024
#define NPIX (HB*HH*WWD)             /* 25088 */
#define SCALE_K 0.17677669529663687f /* 32^-0.5 */

typedef __attribute__((ext_vector_type(8))) short short8;   // 8 bf16 (4 VGPRs)
typedef __attribute__((ext_vector_type(4))) float f32x4;

__device__ inline float toF(float x){ return x; }
__device__ inline float toF(bf16 x){ return __bfloat162float(x); }

__device__ inline float bfu_to_f(unsigned short u){
    union { float f; unsigned u32; } cv; cv.u32 = (unsigned)u << 16; return cv.f;
}

__device__ inline unsigned short f2bu(float f){
    union { bf16 b; unsigned short u; } cv; cv.b = __float2bfloat16(f); return cv.u;
}
__device__ inline unsigned pk2(float a, float b){
    return (unsigned)f2bu(a) | ((unsigned)f2bu(b) << 16);
}

// fast GELU: 0.5*y*(1+tanh(0.79788456*(y+0.044715*y^3))) = y*sigmoid(2u)
__device__ inline float gelu_fast(float y){
    const float u2 = y*y;
    const float arg = y * (2.302208219f + 0.1029402445f*u2);
    const float e2 = exp2f(fminf(arg, 126.0f));
    return y * e2 / (e2 + 1.0f);
}

// async global->LDS, 16B per lane; dest = wave-uniform base + lane*16 (HW adds it)
__device__ inline void gl16(const bf16* g, unsigned short* l){
    __builtin_amdgcn_global_load_lds((const __attribute__((address_space(1))) void*)g,
                                     (__attribute__((address_space(3))) void*)l, 16, 0, 0);
}

// ---- init body: bf16 weights + rope table + concat qkv bias (583 blocks) ----
__device__ inline void init_body(int bid,
    const float* __restrict__ wq, const float* __restrict__ wk,
    const float* __restrict__ wv, const float* __restrict__ wo,
    const float* __restrict__ f1, const float* __restrict__ f2,
    const float* __restrict__ bq, const float* __restrict__ bk,
    const float* __restrict__ bv,
    bf16* __restrict__ dst, float2* __restrict__ ropet, float* __restrict__ bqkv)
{
    const int id = bid*256 + threadIdx.x;   // 149248 total
    if (id < 98304) {
        const float* src; int off;
        if      (id < 8192)  { src = wq; off = id; }
        else if (id < 16384) { src = wk; off = id - 8192; }
        else if (id < 24576) { src = wv; off = id - 16384; }
        else if (id < 32768) { src = wo; off = id - 24576; }
        else if (id < 65536) { src = f1; off = id - 32768; }
        else                 { src = f2; off = id - 65536; }
        const float4 a = *(const float4*)(src + (size_t)off*8);
        const float4 b = *(const float4*)(src + (size_t)off*8 + 4);
        uint4 v; v.x = pk2(a.x,a.y); v.y = pk2(a.z,a.w); v.z = pk2(b.x,b.y); v.w = pk2(b.z,b.w);
        *(uint4*)(dst + (size_t)id*8) = v;
    } else if (id < 148480) {
        const int rid = id - 98304;                // 50176 rope entries
        const int idx = rid >> 4, i = rid & 15;
        const float ph = (float)idx * exp2f(-(float)i * 0.88584749196996324f);
        ropet[rid] = make_float2(cosf(ph), sinf(ph));
    } else {
        const int b = id - 148480;                 // 768 bias
        bqkv[b] = (b < 256) ? bq[b] : ((b < 512) ? bk[b-256] : bv[b-512]);
    }
}

// ---- CPE + LN1 body, sliding-window (1568 blocks) ----
__device__ inline void cpe_ln_body(int bid,
    const float* __restrict__ x, const float* __restrict__ wt,
    const float* __restrict__ bias, const float* __restrict__ g,
    const float* __restrict__ bln, float* __restrict__ X0, bf16* __restrict__ B1)
{
    constexpr int C = 256, VEC = 4, NPX = 4, KS = 3, P = 1, NX = NPX + KS - 1;
    constexpr int GPR = WWD / NPX;          // 14 groups per row
    constexpr int NB  = NPIX / (NPX * 4);   // 1568 blocks
    const int tid  = threadIdx.x;
    const int wv   = tid >> 6;
    const int lane = tid & 63;
    const int swb  = (bid & 7) * (NB >> 3) + (bid >> 3);   // XCD-chunked
    const int gid  = swb * 4 + wv;
    const int row  = gid / GPR;             // 0..447 (b*56 + h)
    const int w0   = (gid % GPR) * NPX;
    const int h    = row % HH;
    const int b    = row / HH;
    const int c0   = lane * VEC;

    float acc[NPX][VEC];
    {
        const float4 b0 = *(const float4*)(bias + c0);
        #pragma unroll
        for (int j = 0; j < NPX; j++) {
            acc[j][0] = b0.x; acc[j][1] = b0.y; acc[j][2] = b0.z; acc[j][3] = b0.w;
        }
    }

    #pragma unroll
    for (int ky = 0; ky < KS; ky++) {
        const int hh = h + ky - P;
        if (hh < 0 || hh >= HH) continue;
        const float* rowp = x + ((size_t)(b*HH + hh) * WWD) * C + c0;
        float wvv[KS][VEC];
        #pragma unroll
        for (int kx = 0; kx < KS; kx++) {
            const float4 w4 = *(const float4*)(wt + (size_t)(ky*KS + kx)*C + c0);
            wvv[kx][0] = w4.x; wvv[kx][1] = w4.y; wvv[kx][2] = w4.z; wvv[kx][3] = w4.w;
        }
        #pragma unroll
        for (int xc = 0; xc < NX; xc++) {
            const int ww = w0 - P + xc;
            float4 f0 = {0.f, 0.f, 0.f, 0.f};
            if (ww >= 0 && ww < WWD) f0 = *(const float4*)(rowp + (size_t)ww*C);
            const float fv[VEC] = {f0.x, f0.y, f0.z, f0.w};
            #pragma unroll
            for (int j = 0; j < NPX; j++) {
                const int kx = xc - j;
                if (kx < 0 || kx >= KS) continue;
                #pragma unroll
                for (int e = 0; e < VEC; e++)
                    acc[j][e] += fv[e] * wvv[kx][e];
            }
        }
    }

    const float4 gv = *(const float4*)(g + c0);
    const float4 bv = *(const float4*)(bln + c0);
    #pragma unroll
    for (int j = 0; j < NPX; j++) {
        const size_t obase = ((size_t)row*WWD + w0 + j)*C + c0;
        {   // + input (residual trunk)
            const float4 r0 = *(const float4*)(x + obase);
            acc[j][0] += r0.x; acc[j][1] += r0.y; acc[j][2] += r0.z; acc[j][3] += r0.w;
        }
        { float4 o; o.x = acc[j][0]; o.y = acc[j][1]; o.z = acc[j][2]; o.w = acc[j][3];
          *(float4*)(X0 + obase) = o; }
        float s1 = acc[j][0] + acc[j][1] + acc[j][2] + acc[j][3];
        float s2 = acc[j][0]*acc[j][0] + acc[j][1]*acc[j][1]
                 + acc[j][2]*acc[j][2] + acc[j][3]*acc[j][3];
        #pragma unroll
        for (int d = 1; d < 64; d <<= 1) { s1 += __shfl_xor(s1, d); s2 += __shfl_xor(s2, d); }
        const float mu  = s1 * (1.0f/DD);
        const float var = s2 * (1.0f/DD) - mu*mu;
        const float inv = rsqrtf(var + 1e-6f);
        uint2 o2;
        o2.x = pk2((acc[j][0]-mu)*inv*gv.x + bv.x, (acc[j][1]-mu)*inv*gv.y + bv.y);
        o2.y = pk2((acc[j][2]-mu)*inv*gv.z + bv.z, (acc[j][3]-mu)*inv*gv.w + bv.w);
        *(uint2*)(B1 + obase) = o2;
    }
}

// ---- sliding-window depthwise conv body, bf16, VEC=8 ch/thread, 4 px/thread ----
template<int KS, bool ADD, int C>
__device__ inline void dwconv_body(int bid,
    const bf16* __restrict__ in, const float* __restrict__ wt, int wst,
    const float* __restrict__ bias, bf16* __restrict__ out)
{
    constexpr int VEC = 8, CG = C/VEC, GPB = 256/CG, NPX = 4, P = KS/2, NX = NPX+KS-1;
    constexpr int GPR = WWD/NPX;          // 14 groups per row
    constexpr int NB  = NPIX/(NPX*GPB);   // grid size
    const int tid = threadIdx.x;
    const int cg  = tid % CG;
    const int gl  = tid / CG;
    const int swb = (bid & 7) * (NB >> 3) + (bid >> 3);   // XCD-chunked
    const int gid = swb * GPB + gl;
    const int row = gid / GPR;            // 0..447 (b*56 + h)
    const int w0  = (gid % GPR) * NPX;
    const int h   = row % HH;
    const int b   = row / HH;
    const int c0  = cg * VEC;

    float acc[NPX][VEC];
    {
        const float4 b0 = *(const float4*)(bias + c0);
        const float4 b1 = *(const float4*)(bias + c0 + 4);
        #pragma unroll
        for (int j = 0; j < NPX; j++) {
            acc[j][0]=b0.x; acc[j][1]=b0.y; acc[j][2]=b0.z; acc[j][3]=b0.w;
            acc[j][4]=b1.x; acc[j][5]=b1.y; acc[j][6]=b1.z; acc[j][7]=b1.w;
        }
    }

    #pragma unroll
    for (int ky = 0; ky < KS; ky++) {
        const int hh = h + ky - P;
        if (hh < 0 || hh >= HH) continue;
        const bf16* rowp = in + ((size_t)(b*HH + hh) * WWD) * C + c0;
        float wv[KS][VEC];
        #pragma unroll
        for (int kx = 0; kx < KS; kx++) {
            const float* wp = wt + (size_t)(ky*KS + kx)*wst + c0;
            const float4 w0v = *(const float4*)(wp);
            const float4 w1v = *(const float4*)(wp + 4);
            wv[kx][0]=w0v.x; wv[kx][1]=w0v.y; wv[kx][2]=w0v.z; wv[kx][3]=w0v.w;
            wv[kx][4]=w1v.x; wv[kx][5]=w1v.y; wv[kx][6]=w1v.z; wv[kx][7]=w1v.w;
        }
        #pragma unroll
        for (int x = 0; x < NX; x++) {
            const int ww = w0 - P + x;
            short8 raw = {0,0,0,0,0,0,0,0};
            if (ww >= 0 && ww < WWD) raw = *(const short8*)(rowp + (size_t)ww*C);
            float f[VEC];
            #pragma unroll
            for (int e = 0; e < VEC; e++) f[e] = bfu_to_f((unsigned short)raw[e]);
            #pragma unroll
            for (int j = 0; j < NPX; j++) {
                const int kx = x - j;
                if (kx < 0 || kx >= KS) continue;
                #pragma unroll
                for (int e = 0; e < VEC; e++)
                    acc[j][e] += f[e] * wv[kx][e];
            }
        }
    }

    #pragma unroll
    for (int j = 0; j < NPX; j++) {
        const size_t obase = ((size_t)row*WWD + w0 + j)*C + c0;
        if constexpr (ADD) {
            short8 vv = *(const short8*)(in + obase);
            #pragma unroll
            for (int e = 0; e < VEC; e++) acc[j][e] += bfu_to_f((unsigned short)vv[e]);
        }
        uint4 o;
        o.x = pk2(acc[j][0], acc[j][1]); o.y = pk2(acc[j][2], acc[j][3]);
        o.z = pk2(acc[j][4], acc[j][5]); o.w = pk2(acc[j][6], acc[j][7]);
        *(uint4*)(out + obase) = o;
    }
}

// ---- MFMA decomposed attention body, in-register softmax, setprio'd MFMA ----
template<bool COLM>
__device__ inline void attn_body(int bid,
    const bf16* __restrict__ q, const bf16* __restrict__ k,
    const bf16* __restrict__ v, const bf16* __restrict__ lepe,
    bf16* __restrict__ outp)
{
    __shared__ unsigned short Qb[64*40];
    __shared__ unsigned short Kb[64*40];
    __shared__ unsigned short Vt[32*80];
    __shared__ unsigned short Pb[64*72];

    const int line = bid % 56;
    const int nh   = (bid / 56) % NHEAD;
    const int b    = bid / (56 * NHEAD);
    const int tid  = threadIdx.x;
    const int wid  = tid >> 6;
    const int lane = tid & 63;
    const int quad = lane >> 4;
    const int l15  = lane & 15;

    const size_t rstr = COLM ? (size_t)WWD * DD : (size_t)DD;
    const size_t base = COLM ? (((size_t)b*HH*WWD + line) * DD + nh*KDIM)
                             : (((size_t)(b*HH + line) * WWD) * DD + nh*KDIM);

    {
        const int r  = tid >> 2;
        const int cc = tid & 3;
        uint4 zero = {0,0,0,0};
        if (r < 56) {
            size_t gg = base + (size_t)r * rstr + cc*8;
            *(uint4*)(&Qb[r*40 + cc*8]) = *(const uint4*)(q + gg);
            *(uint4*)(&Kb[r*40 + cc*8]) = *(const uint4*)(k + gg);
        } else {
            *(uint4*)(&Qb[r*40 + cc*8]) = zero;
            *(uint4*)(&Kb[r*40 + cc*8]) = zero;
        }
        uint4 vv = zero;
        if (lane < 56)
            vv = *(const uint4*)(v + base + (size_t)lane * rstr + wid*8);
        const unsigned short* pv = (const unsigned short*)&vv;
        #pragma unroll
        for (int e = 0; e < 8; e++)
            Vt[(wid*8 + e)*80 + lane] = pv[e];
    }
    __syncthreads();

    {
        short8 af = *(const short8*)(&Qb[(wid*16 + l15)*40 + quad*8]);
        f32x4 s_[4];
        __builtin_amdgcn_s_setprio(1);
        #pragma unroll
        for (int j = 0; j < 4; j++) {
            short8 bfm = *(const short8*)(&Kb[(j*16 + l15)*40 + quad*8]);
            f32x4 z = {0.f,0.f,0.f,0.f};
            s_[j] = __builtin_amdgcn_mfma_f32_16x16x32_bf16(af, bfm, z, 0, 0, 0);
        }
        __builtin_amdgcn_s_setprio(0);
        const bool v3 = (l15 < 8);
        float mx[4], sm[4];
        #pragma unroll
        for (int reg = 0; reg < 4; reg++) {
            float m01 = fmaxf(s_[0][reg], s_[1][reg]);
            float m23 = v3 ? fmaxf(s_[2][reg], s_[3][reg]) : s_[2][reg];
            mx[reg] = fmaxf(m01, m23);
        }
        #pragma unroll
        for (int d = 1; d < 16; d <<= 1) {
            #pragma unroll
            for (int reg = 0; reg < 4; reg++)
                mx[reg] = fmaxf(mx[reg], __shfl_xor(mx[reg], d));
        }
        float e_[4][4];
        #pragma unroll
        for (int reg = 0; reg < 4; reg++) sm[reg] = 0.f;
        #pragma unroll
        for (int j = 0; j < 4; j++) {
            #pragma unroll
            for (int reg = 0; reg < 4; reg++) {
                const bool valid = (j < 3) || v3;
                float ex = valid ? expf(s_[j][reg] - mx[reg]) : 0.f;
                e_[j][reg] = ex;
                sm[reg] += ex;
            }
        }
        #pragma unroll
        for (int d = 1; d < 16; d <<= 1) {
            #pragma unroll
            for (int reg = 0; reg < 4; reg++)
                sm[reg] += __shfl_xor(sm[reg], d);
        }
        float inv[4];
        #pragma unroll
        for (int reg = 0; reg < 4; reg++) inv[reg] = 1.0f / sm[reg];
        #pragma unroll
        for (int j = 0; j < 4; j++)
            #pragma unroll
            for (int reg = 0; reg < 4; reg++)
                Pb[(wid*16 + quad*4 + reg)*72 + j*16 + l15] = f2bu(e_[j][reg] * inv[reg]);
    }
    __syncthreads();

    {
        f32x4 acc[2];
        acc[0] = (f32x4){0.f,0.f,0.f,0.f};
        acc[1] = (f32x4){0.f,0.f,0.f,0.f};
        __builtin_amdgcn_s_setprio(1);
        #pragma unroll
        for (int k0 = 0; k0 < 64; k0 += 32) {
            short8 af = *(const short8*)(&Pb[(wid*16 + l15)*72 + k0 + quad*8]);
            #pragma unroll
            for (int nt = 0; nt < 2; nt++) {
                short8 bfm = *(const short8*)(&Vt[(nt*16 + l15)*80 + k0 + quad*8]);
                acc[nt] = __builtin_amdgcn_mfma_f32_16x16x32_bf16(af, bfm, acc[nt], 0, 0, 0);
            }
        }
        __builtin_amdgcn_s_setprio(0);
        #pragma unroll
        for (int nt = 0; nt < 2; nt++) {
            #pragma unroll
            for (int reg = 0; reg < 4; reg++) {
                const int m = wid*16 + quad*4 + reg;
                const int d = nt*16 + l15;
                if (m < 56) {
                    float val = acc[nt][reg];
                    if (COLM) {
                        int hp = 7*nh + (m >> 3);
                        int wp = (m & 7)*7 + (line >> 3);
                        int cp = (line & 7)*32 + d;
                        size_t o = ((size_t)(b*HH + hp)*WWD + wp)*DD + cp;
                        outp[o] = __float2bfloat16(val + toF(lepe[o]));
                    } else {
                        outp[base + (size_t)m * rstr + d] = __float2bfloat16(val);
                    }
                }
            }
        }
    }
}

// ---- fused: init (583 blocks) + CPE/LN1 (1568 blocks) ----
__global__ __launch_bounds__(256) void init_cpe_kernel(
    const float* wq, const float* wk, const float* wv, const float* wo,
    const float* f1, const float* f2, const float* bq, const float* bk,
    const float* bv, bf16* dst, float2* ropet, float* bqkv,
    const float* x, const float* cwt, const float* cb,
    const float* g, const float* bln, float* X0, bf16* B1)
{
    if (blockIdx.x < 583)
        init_body(blockIdx.x, wq, wk, wv, wo, f1, f2, bq, bk, bv, dst, ropet, bqkv);
    else
        cpe_ln_body(blockIdx.x - 583, x, cwt, cb, g, bln, X0, B1);
}

// ---- fused: ROW attention (3584 blocks) + LEPE dwconv5x5 (784 blocks) ----
__global__ __launch_bounds__(256) void attn_lepe_kernel(
    const bf16* q, const bf16* k, const bf16* v,
    const float* lepe_w, const float* lepe_b, bf16* lepe_out,
    bf16* vw_out)
{
    if (blockIdx.x < 3584)
        attn_body<false>(blockIdx.x, q, k, v, nullptr, vw_out);
    else
        dwconv_body<5, false, 256>(blockIdx.x - 3584, v, lepe_w, DD, lepe_b, lepe_out);
}

// ---- standalone wrappers ----
__global__ __launch_bounds__(256) void attn_col_kernel(
    const bf16* q, const bf16* k, const bf16* v, const bf16* lepe, bf16* outp)
{
    attn_body<true>(blockIdx.x, q, k, v, lepe, outp);
}

__global__ __launch_bounds__(256) void dwconv_ffn_kernel(
    const bf16* in, const float* wt, const float* bias, bf16* out)
{
    dwconv_body<3, true, 1024>(blockIdx.x, in, wt, FFND, bias, out);
}

// ---- MFMA GEMM: 128x128 tile, 4 waves (2x2), acc[4][4], BK=32, bf16 weights.
// Depth-2 pipeline (3 LDS buffers, gl16, counted vmcnt) + T2 swizzle.
// EPI: 1 = fast-GELU bf16 out, 3 = QKV fused (seg 0=q(rope),1=k(rope+scale),2=v).
template<int EPI, int ROPE>
__global__ __launch_bounds__(256) void mgemm128_kernel(
    const bf16* __restrict__ A, const bf16* __restrict__ Wb, int ldw,
    const float* __restrict__ bias, const float2* __restrict__ ropet,
    const float* __restrict__ residF, float* __restrict__ accF,
    bf16* __restrict__ outB, bf16* __restrict__ outK, bf16* __restrict__ outV,
    int M, int N, int K, float scale)
{
    __shared__ __align__(16) unsigned short Sh[24576];  // 48KB: 3 x (As 8KB | Bs 8KB)
    const int tid  = threadIdx.x;
    const int wid  = tid >> 6;
    const int lane = tid & 63;
    const int quad = lane >> 4;
    const int l15  = lane & 15;
    const int wr   = wid >> 1;
    const int wc   = wid & 1;
    const int sw   = (l15 >> 1) & 3;     // frag-read chunk swizzle (= (row>>1)&3)

    // XCD-chunked tile swizzle (T divisible by 8)
    const int NXg = gridDim.x;
    const int T   = NXg * gridDim.y;
    int f = blockIdx.y * NXg + blockIdx.x;
    f = (f & 7) * (T >> 3) + (f >> 3);
    const int row0 = (f / NXg) * 128;
    const int col0 = (f % NXg) * 128;

    f32x4 acc[4][4];
    #pragma unroll
    for (int m = 0; m < 4; m++)
        #pragma unroll
        for (int n = 0; n < 4; n++)
            acc[m][n] = (f32x4){0.f, 0.f, 0.f, 0.f};

    const int ob0 = (wid*2 + 0)*64;          // wave-uniform 16B-unit bases
    const int ob1 = (wid*2 + 1)*64;
    const int o0  = ob0 + lane, o1 = ob1 + lane;
    const int rA0 = o0 >> 2, ch0 = ((o0 & 3) ^ ((o0 >> 3) & 3)) * 8;
    const int rA1 = o1 >> 2, ch1 = ((o1 & 3) ^ ((o1 >> 3) & 3)) * 8;
    const bf16* pA0 = A  + (size_t)(row0 + rA0)*K   + ch0;
    const bf16* pA1 = A  + (size_t)(row0 + rA1)*K   + ch1;
    const bf16* pW0 = Wb + (size_t)(col0 + rA0)*ldw + ch0;
    const bf16* pW1 = Wb + (size_t)(col0 + rA1)*ldw + ch1;

    #define STAGE(bi) { unsigned short* As_ = Sh + (bi)*8192;                  \
                        unsigned short* Bs_ = As_ + 4096;                      \
                        gl16(pA0, &As_[ob0*8]); gl16(pA1, &As_[ob1*8]);        \
                        gl16(pW0, &Bs_[ob0*8]); gl16(pW1, &Bs_[ob1*8]);        \
                        pA0 += 32; pA1 += 32; pW0 += 32; pW1 += 32; }

    #define COMPUTE(bi) { const unsigned short* As_ = Sh + (bi)*8192;          \
                          const unsigned short* Bs_ = As_ + 4096;              \
                          short8 af[4], bfr[4];                                \
                          _Pragma("unroll")                                    \
                          for (int m = 0; m < 4; m++)                          \
                              af[m] = *(const short8*)(&As_[(wr*64 + m*16 + l15)*32 + (quad ^ sw)*8]); \
                          _Pragma("unroll")                                    \
                          for (int n = 0; n < 4; n++)                          \
                              bfr[n] = *(const short8*)(&Bs_[(wc*64 + n*16 + l15)*32 + (quad ^ sw)*8]); \
                          _Pragma("unroll")                                    \
                          for (int m = 0; m < 4; m++)                          \
                              _Pragma("unroll")                                \
                              for (int n = 0; n < 4; n++)                      \
                                  acc[m][n] = __builtin_amdgcn_mfma_f32_16x16x32_bf16(af[m], bfr[n], acc[m][n], 0, 0, 0); }

    const int nt = K >> 5;                      // 8, always >= 3
    STAGE(0); STAGE(1);                         // tiles 0,1 in flight
    int cur = 0;
    for (int t = 0; t < nt; t++) {
        if (t + 2 < nt) {
            const int nx = (cur == 0) ? 2 : ((cur == 1) ? 0 : 1);   // (cur+2)%3
            STAGE(nx);                          // tile t+2 -> third buf (in flight)
            asm volatile("s_waitcnt vmcnt(8)" ::: "memory");        // tile t landed
        } else if (t + 1 < nt) {
            asm volatile("s_waitcnt vmcnt(4)" ::: "memory");
        } else {
            asm volatile("s_waitcnt vmcnt(0)" ::: "memory");
        }
        __builtin_amdgcn_s_barrier();           // all waves' tile-t loads landed
        COMPUTE(cur);
        if (t + 1 < nt) __builtin_amdgcn_s_barrier();  // done reading before overwrite
        cur = (cur == 2) ? 0 : cur + 1;
    }
    #undef STAGE
    #undef COMPUTE

    // ---- epilogue: per-wave LDS transpose -> coalesced stores ----
    __syncthreads();
    float* Ls = (float*)Sh;                  // 4 waves x 16 x 68 floats = 17408B
    const int cbl = l15 * 4;
    const int seg = (EPI == 3) ? (col0 >> 8) : 0;
    bf16* dst = outB;
    if (EPI == 3) dst = (seg == 0) ? outB : ((seg == 1) ? outK : outV);
    const float esc = (EPI == 3) ? ((seg == 1) ? scale : 1.0f) : scale;
    const bool doRope = ROPE && (EPI != 3 || seg < 2);

    #pragma unroll
    for (int m = 0; m < 4; m++) {
        #pragma unroll
        for (int n = 0; n < 4; n++) {
            const int col = n*16 + l15;
            const float bval = bias[col0 + wc*64 + col];
            #pragma unroll
            for (int reg = 0; reg < 4; reg++) {
                float y = (acc[m][n][reg] + bval) * esc;
                if (EPI == 1) y = gelu_fast(y);
                Ls[wid*1088 + (quad*4+reg)*68 + col] = y;
            }
        }
        #pragma unroll
        for (int p = 0; p < 4; p++) {
            const int rowt = p*4 + quad;
            const float4 v = *(const float4*)&Ls[wid*1088 + rowt*68 + cbl];
            const int mm = row0 + wr*64 + m*16 + rowt;
            const int ncl = (EPI == 3) ? ((col0 & 255) + wc*64 + cbl)
                                       : (col0 + wc*64 + cbl);
            const size_t o = (EPI == 3) ? ((size_t)mm * 256 + ncl)
                                        : ((size_t)mm * N + ncl);
            float a = v.x, b = v.y, c = v.z, d = v.w;
            if (doRope) {
                const int idx = mm % (HH*WWD);
                const int i0 = (ncl & 31) >> 1;   // even -> float4-aligned
                const float4 t = *(const float4*)&ropet[(size_t)idx*16 + i0];
                const float na  = a*t.x - b*t.y;
                const float nb  = b*t.x + a*t.y;
                const float ncv = c*t.z - d*t.w;
                const float nd  = d*t.z + c*t.w;
                a = na; b = nb; c = ncv; d = nd;
            }
            uint2 ov; ov.x = pk2(a, b); ov.y = pk2(c, d);
            *(uint2*)(dst + o) = ov;
        }
    }
}

// ---- 512-thread 128x256-tile GEMM (N=256), K via arg. 8 waves (2 row x 4 col),
// depth-2 gl16 pipeline (3 x 24KB LDS buffers), T2 swizzle. Epilogues:
// DOLN=1: WO+residual+LN2 (accF = x1, outB = LN(x1) bf16)
// DOLN=0: fc2+residual     (accF = residF + GEMM + bias, fp32 final out)
template<int DOLN>
__global__ __launch_bounds__(512) void mgemm_wide_kernel(
    const bf16* __restrict__ A, const bf16* __restrict__ Wb,
    const float* __restrict__ bias, const float* __restrict__ residF,
    float* __restrict__ accF, const float* __restrict__ g,
    const float* __restrict__ bln, bf16* __restrict__ outB, int K)
{
    __shared__ __align__(16) unsigned short Sh[36864];  // 72KB: 3 x (As 8KB | Bs 16KB)
    const int tid  = threadIdx.x;
    const int wid  = tid >> 6;          // 0..7
    const int lane = tid & 63;
    const int quad = lane >> 4;
    const int l15  = lane & 15;
    const int wr   = wid >> 2;          // 0..1  (64-row half)
    const int wc   = wid & 3;           // 0..3  (64-col quarter)
    const int sw   = (l15 >> 1) & 3;
    const int row0 = blockIdx.x * 128;

    f32x4 acc[4][4];
    #pragma unroll
    for (int m = 0; m < 4; m++)
        #pragma unroll
        for (int n = 0; n < 4; n++)
            acc[m][n] = (f32x4){0.f, 0.f, 0.f, 0.f};

    // staging: unit = wid*64 + lane; row = unit>>2; chunk pre-swizzled
    const int rU = wid*16 + (lane >> 2);                    // 0..127
    const int ch = ((lane & 3) ^ ((lane >> 3) & 3)) * 8;    // swizzled chunk
    const bf16* pA  = A  + (size_t)(row0 + rU)*K + ch;
    const bf16* pB1 = Wb + (size_t)rU*K + ch;               // W rows 0..127
    const bf16* pB2 = Wb + (size_t)(128 + rU)*K + ch;       // W rows 128..255

    #define STAGE(bi) { unsigned short* As_ = Sh + (bi)*12288;                 \
                        unsigned short* Bs_ = As_ + 4096;                      \
                        gl16(pA,  &As_[wid*512]);                              \
                        gl16(pB1, &Bs_[wid*512]);                              \
                        gl16(pB2, &Bs_[4096 + wid*512]);                       \
                        pA += 32; pB1 += 32; pB2 += 32; }

    #define COMPUTE(bi) { const unsigned short* As_ = Sh + (bi)*12288;         \
                          const unsigned short* Bs_ = As_ + 4096;              \
                          short8 af[4], bfr[4];                                \
                          _Pragma("unroll")                                    \
                          for (int m = 0; m < 4; m++)                          \
                              af[m] = *(const short8*)(&As_[(wr*64 + m*16 + l15)*32 + (quad ^ sw)*8]); \
                          _Pragma("unroll")                                    \
                          for (int n = 0; n < 4; n++)                          \
                              bfr[n] = *(const short8*)(&Bs_[(wc*64 + n*16 + l15)*32 + (quad ^ sw)*8]); \
                          _Pragma("unroll")                                    \
                          for (int m = 0; m < 4; m++)                          \
                              _Pragma("unroll")                                \
                              for (int n = 0; n < 4; n++)                      \
                                  acc[m][n] = __builtin_amdgcn_mfma_f32_16x16x32_bf16(af[m], bfr[n], acc[m][n], 0, 0, 0); }

    const int nt = K >> 5;                      // 8 (wo) or 32 (fc2), >= 3
    STAGE(0); STAGE(1);                         // tiles 0,1 in flight
    int cur = 0;
    for (int t = 0; t < nt; t++) {
        if (t + 2 < nt) {
            const int nx = (cur == 0) ? 2 : ((cur == 1) ? 0 : 1);   // (cur+2)%3
            STAGE(nx);                          // tile t+2 in flight
            asm volatile("s_waitcnt vmcnt(6)" ::: "memory");        // tile t landed
        } else if (t + 1 < nt) {
            asm volatile("s_waitcnt vmcnt(3)" ::: "memory");
        } else {
            asm volatile("s_waitcnt vmcnt(0)" ::: "memory");
        }
        __builtin_amdgcn_s_barrier();
        COMPUTE(cur);
        if (t + 1 < nt) __builtin_amdgcn_s_barrier();
        cur = (cur == 2) ? 0 : cur + 1;
    }
    #undef STAGE
    #undef COMPUTE

    // ---- epilogue ----
    __syncthreads();
    float* Ls = (float*)Sh;                  // 8 waves x 1088 floats = 34816B
    float* SL = Ls + 8*1088;                 // 128 rows x 8 floats = 4KB
    const int cbl = l15 * 4;
    float4 stash[4][4];

    #pragma unroll
    for (int m = 0; m < 4; m++) {
        #pragma unroll
        for (int n = 0; n < 4; n++) {
            const float bval = bias[wc*64 + n*16 + l15];
            const int col = n*16 + l15;
            #pragma unroll
            for (int reg = 0; reg < 4; reg++)
                Ls[wid*1088 + (quad*4+reg)*68 + col] = acc[m][n][reg] + bval;
        }
        #pragma unroll
        for (int p = 0; p < 4; p++) {
            const int rowt = p*4 + quad;
            const float4 v = *(const float4*)&Ls[wid*1088 + rowt*68 + cbl];
            const int rl = wr*64 + m*16 + rowt;
            const size_t o = (size_t)(row0 + rl) * 256 + wc*64 + cbl;
            const float4 rv = *(const float4*)(residF + o);
            float4 w; w.x = v.x+rv.x; w.y = v.y+rv.y; w.z = v.z+rv.z; w.w = v.w+rv.w;
            *(float4*)(accF + o) = w;
            if (DOLN) {
                stash[m][p] = w;
                float ls1 = w.x + w.y + w.z + w.w;
                float ls2 = w.x*w.x + w.y*w.y + w.z*w.z + w.w*w.w;
                #pragma unroll
                for (int d = 1; d < 16; d <<= 1) {
                    ls1 += __shfl_xor(ls1, d);
                    ls2 += __shfl_xor(ls2, d);
                }
                if (l15 == 0) { SL[rl*8 + wc*2] = ls1; SL[rl*8 + wc*2 + 1] = ls2; }
            }
        }
    }
    if (DOLN) {
        __syncthreads();
        if (tid < 128) {
            const int row = tid;
            const float s1 = SL[row*8] + SL[row*8+2] + SL[row*8+4] + SL[row*8+6];
            const float s2 = SL[row*8+1] + SL[row*8+3] + SL[row*8+5] + SL[row*8+7];
            const float mu  = s1 * (1.0f/256.0f);
            const float var = s2 * (1.0f/256.0f) - mu*mu;
            SL[row*8]   = mu;
            SL[row*8+1] = rsqrtf(var + 1e-6f);
        }
        __syncthreads();
        const float4 g4 = *(const float4*)(g   + wc*64 + cbl);
        const float4 b4 = *(const float4*)(bln + wc*64 + cbl);
        #pragma unroll
        for (int m = 0; m < 4; m++) {
            #pragma unroll
            for (int p = 0; p < 4; p++) {
                const int rl = wr*64 + m*16 + p*4 + quad;
                const float mu  = SL[rl*8];
                const float inv = SL[rl*8+1];
                const float4 w = stash[m][p];
                uint2 ov;
                ov.x = pk2((w.x-mu)*inv*g4.x + b4.x, (w.y-mu)*inv*g4.y + b4.y);
                ov.y = pk2((w.z-mu)*inv*g4.z + b4.z, (w.w-mu)*inv*g4.w + b4.w);
                *(uint2*)(outB + (size_t)(row0 + rl)*256 + wc*64 + cbl) = ov;
            }
        }
    }
}

extern "C" void kernel_launch(void* const* d_in, const int* in_sizes, int n_in,
                              void* d_out, int out_size, void* d_ws, size_t ws_size,
                              hipStream_t stream)
{
    const float* x_in   = (const float*)d_in[0];
    const float* cpe_w  = (const float*)d_in[1];
    const float* cpe_b  = (const float*)d_in[2];
    const float* ln1_g  = (const float*)d_in[3];
    const float* ln1_b  = (const float*)d_in[4];
    const float* wq     = (const float*)d_in[5];
    const float* bq     = (const float*)d_in[6];
    const float* wk     = (const float*)d_in[7];
    const float* bk     = (const float*)d_in[8];
    const float* wv     = (const float*)d_in[9];
    const float* bv     = (const float*)d_in[10];
    const float* lepe_w = (const float*)d_in[11];
    const float* lepe_b = (const float*)d_in[12];
    const float* wo     = (const float*)d_in[13];
    const float* bo     = (const float*)d_in[14];
    const float* ln2_g  = (const float*)d_in[15];
    const float* ln2_b  = (const float*)d_in[16];
    const float* fc1_w  = (const float*)d_in[17];
    const float* fc1_b  = (const float*)d_in[18];
    const float* dw_w   = (const float*)d_in[19];
    const float* dw_b   = (const float*)d_in[20];
    const float* fc2_w  = (const float*)d_in[21];
    const float* fc2_b  = (const float*)d_in[22];
    float* out = (float*)d_out;

    const size_t ND = (size_t)NPIX * DD;
    const size_t NF = (size_t)NPIX * FFND;          // 4*ND
    char* ws = (char*)d_ws;
    float*  X0    = (float*)(ws);                          // ND fp32
    float*  ACC   = (float*)(ws + ND*4);                   // ND fp32
    bf16*   B1    = (bf16*) (ws + ND*8);                   // ND bf16 (xn1 / lepe)
    bf16*   B2    = (bf16*) (ws + ND*8 + ND*2);            // ND bf16 (q / xn2)
    bf16*   H1    = (bf16*) (ws + ND*8 + ND*4);            // NF bf16 (k alias / fc1 out)
    bf16*   H2    = (bf16*) (ws + ND*8 + ND*4 + NF*2);     // NF bf16 (v alias / dw out)
    bf16*   WB    = (bf16*) (ws + ND*8 + ND*4 + NF*4);     // 786432 bf16 weights
    float2* ROPET = (float2*)(ws + ND*8 + ND*4 + NF*4 + 786432*2); // 50176 float2
    float*  BQKV  = (float*) (ws + ND*8 + ND*4 + NF*4 + 786432*2 + 50176*8); // 768 f32
    bf16*   B3 = H1;                    // k (dead before fc1 writes)
    bf16*   B4 = H2;                    // v (dead before dw writes)
    bf16*   VWb   = (bf16*)d_out;       // d_out lo half: vw scratch
    bf16*   ATTNb = VWb + ND;           // d_out hi half: attn scrambled scratch

    const bf16* WOb = WB + 196608;
    const bf16* F1b = WB + 262144;
    const bf16* F2b = WB + 524288;

    dim3 b256(256);
    dim3 gridQKV(768/128, NPIX/128); // (6, 196)  T=1176
    dim3 gridF(FFND/128, NPIX/128);  // (8, 196)  T=1568

    // 1. fused init (weights/rope/bias) + CPE/LN1  [independent block ranges]
    init_cpe_kernel<<<583 + NPIX/16, b256, 0, stream>>>(
        wq, wk, wv, wo, fc1_w, fc2_w, bq, bk, bv, WB, ROPET, BQKV,
        x_in, cpe_w, cpe_b, ln1_g, ln1_b, X0, B1);
    // 2. fused QKV projection (N=768 concat weights); rope on q,k; scale on k
    mgemm128_kernel<3,1><<<gridQKV, b256, 0, stream>>>(B1, WB, DD, BQKV, ROPET,
                                                       nullptr, nullptr, B2, B3, B4,
                                                       NPIX, 768, DD, SCALE_K);
    // 3. fused ROW attention (3584 blocks) + LEPE dwconv5x5 (784 blocks)
    attn_lepe_kernel<<<3584 + 784, b256, 0, stream>>>(B2, B3, B4, lepe_w, lepe_b, B1, VWb);
    // 4. Column attention; scrambled write + lepe -> ATTNb
    attn_col_kernel<<<HB*NHEAD*WWD, b256, 0, stream>>>(B2, B3, VWb, B1, ATTNb);
    // 5. WO projection + residual + LN2 fused: ACC = X0 + ATTNb*wo^T + bo; B2 = LN(ACC)
    mgemm_wide_kernel<1><<<196, dim3(512), 0, stream>>>(ATTNb, WOb, bo, X0, ACC,
                                                        ln2_g, ln2_b, B2, 256);
    // 6. fc1 (N=1024, 128x128 tiles, depth-2) + fast GELU -> H1
    mgemm128_kernel<1,0><<<gridF, b256, 0, stream>>>(B2, F1b, DD, fc1_b, nullptr,
                                                     nullptr, nullptr, H1, nullptr, nullptr,
                                                     NPIX, FFND, DD, 1.0f);
    // 7. dwconv3x3 over 1024 channels + identity -> H2
    dwconv_ffn_kernel<<<3136, b256, 0, stream>>>(H1, dw_w, dw_b, H2);
    // 8. fc2 (K=1024, 128x256 wide tile, depth-2) + residual: out = ACC + H2*fc2^T + b
    mgemm_wide_kernel<0><<<196, dim3(512), 0, stream>>>(H2, F2b, fc2_b, ACC, out,
                                                        nullptr, nullptr, nullptr, 1024);
}